// Round 4
// baseline (458.018 us; speedup 1.0000x reference)
//
#include <hip/hip_runtime.h>

typedef __bf16 bf16_t;
typedef __bf16 bf16x8 __attribute__((ext_vector_type(8)));
typedef float  f32x4  __attribute__((ext_vector_type(4)));

#define MFMA(a, b, c) __builtin_amdgcn_mfma_f32_16x16x32_bf16((a), (b), (c), 0, 0, 0)

static constexpr int Bsz = 2, S = 2048, D = 1024, H = 16, DK = 64;

__device__ __forceinline__ float scrub(float v, float lo, float hi) {
    return fminf(fmaxf(v, lo), hi);  // IEEE fmin/fmax drop NaN
}

// load 8 contiguous elements as bf16x8 (converting if source is f32)
__device__ __forceinline__ bf16x8 ld8(const bf16_t* p) { return *(const bf16x8*)p; }
__device__ __forceinline__ bf16x8 ld8(const float* p) {
    float4 a = *(const float4*)p;
    float4 b = *(const float4*)(p + 4);
    bf16x8 r;
    r[0] = (bf16_t)a.x; r[1] = (bf16_t)a.y; r[2] = (bf16_t)a.z; r[3] = (bf16_t)a.w;
    r[4] = (bf16_t)b.x; r[5] = (bf16_t)b.y; r[6] = (bf16_t)b.z; r[7] = (bf16_t)b.w;
    return r;
}

// ---------------------------------------------------------------------------
// GEMM: C[M,N] = A[M,K] * B[N,K]^T + bias[N]; fp32 accum, bf16 MFMA.
// TA/TB/TC = float or bf16_t. 128x128 tile, BK=32, 256 threads.
// ---------------------------------------------------------------------------
template <typename TA, typename TB, typename TC>
__global__ __launch_bounds__(256) void gemm_bt(
    const TA* __restrict__ A, const TB* __restrict__ B,
    const float* __restrict__ bias, TC* __restrict__ C,
    int M, int N, int K)
{
    __shared__ bf16_t As[128][40];
    __shared__ bf16_t Bs[128][40];

    const int t    = threadIdx.x;
    const int wave = t >> 6, lane = t & 63;
    const int quad = lane >> 4, l15 = lane & 15;
    const int wm = (wave >> 1) * 64, wn = (wave & 1) * 64;
    const int rowbase = blockIdx.y * 128, colbase = blockIdx.x * 128;

    f32x4 acc[4][4];
#pragma unroll
    for (int i = 0; i < 4; ++i)
#pragma unroll
        for (int j = 0; j < 4; ++j) acc[i][j] = {0.f, 0.f, 0.f, 0.f};

    for (int kt = 0; kt < K; kt += 32) {
        __syncthreads();
#pragma unroll
        for (int c = 0; c < 2; ++c) {
            int f  = t + 256 * c;
            int r  = f >> 2;
            int cc = (f & 3) << 3;
            *(bf16x8*)&As[r][cc] = ld8(&A[(size_t)(rowbase + r) * K + kt + cc]);
            *(bf16x8*)&Bs[r][cc] = ld8(&B[(size_t)(colbase + r) * K + kt + cc]);
        }
        __syncthreads();

        bf16x8 af[4], bfr[4];
#pragma unroll
        for (int mt = 0; mt < 4; ++mt)
            af[mt] = *(const bf16x8*)&As[wm + mt * 16 + l15][quad * 8];
#pragma unroll
        for (int nt = 0; nt < 4; ++nt)
            bfr[nt] = *(const bf16x8*)&Bs[wn + nt * 16 + l15][quad * 8];
#pragma unroll
        for (int mt = 0; mt < 4; ++mt)
#pragma unroll
            for (int nt = 0; nt < 4; ++nt)
                acc[mt][nt] = MFMA(af[mt], bfr[nt], acc[mt][nt]);
    }

#pragma unroll
    for (int nt = 0; nt < 4; ++nt) {
        int col  = colbase + wn + nt * 16 + l15;
        float bv = bias[col];
#pragma unroll
        for (int mt = 0; mt < 4; ++mt) {
            int row0 = rowbase + wm + mt * 16 + quad * 4;
#pragma unroll
            for (int r = 0; r < 4; ++r)
                C[(size_t)(row0 + r) * N + col] = (TC)(acc[mt][nt][r] + bv);
        }
    }
}

// ---------------------------------------------------------------------------
// Flash attention (causal, V == K). Q/K are internal bf16 buffers.
// Block = (b, h, 64-row q-tile), 4 waves. Writes O (bf16, concat layout)
// and per-row (m, 1/l) stats.
// ---------------------------------------------------------------------------
__global__ __launch_bounds__(256) void attn_flash(
    const bf16_t* __restrict__ Q, const bf16_t* __restrict__ Km,
    bf16_t* __restrict__ Oc, float* __restrict__ m_ws, float* __restrict__ il_ws)
{
    const int qt = (int)gridDim.x - 1 - (int)blockIdx.x;
    const int h  = blockIdx.y, b = blockIdx.z;
    const int t  = threadIdx.x;
    const int wave = t >> 6, lane = t & 63;
    const int quad = lane >> 4, l15 = lane & 15;

    __shared__ bf16_t Qs[64][72];
    __shared__ bf16_t Ks[64][72];
    __shared__ bf16_t Vt[64][72];
    __shared__ bf16_t Ps[64][72];

    for (int i = t; i < 64 * 72 / 2; i += 256) {
        ((int*)Qs)[i] = 0; ((int*)Ks)[i] = 0; ((int*)Vt)[i] = 0; ((int*)Ps)[i] = 0;
    }
    __syncthreads();

    const size_t qrow0 = (size_t)b * S + (size_t)qt * 64;
    const int hcol = h * DK;

#pragma unroll
    for (int p = 0; p < 2; ++p) {
        int jr = p * 32 + (t >> 3);
        int ce = (t & 7) * 8;
        *(bf16x8*)&Qs[jr][ce] = *(const bf16x8*)&Q[(qrow0 + jr) * D + hcol + ce];
    }
    __syncthreads();
    const bf16x8 qf0 = *(const bf16x8*)&Qs[wave * 16 + l15][quad * 8];
    const bf16x8 qf1 = *(const bf16x8*)&Qs[wave * 16 + l15][32 + quad * 8];

    f32x4 accO[4];
#pragma unroll
    for (int u = 0; u < 4; ++u) accO[u] = {0.f, 0.f, 0.f, 0.f};
    float mrow[4] = {-1e30f, -1e30f, -1e30f, -1e30f};
    float lrow[4] = {0.f, 0.f, 0.f, 0.f};

    const int irow0 = qt * 64 + wave * 16 + quad * 4;

    for (int jt = 0; jt <= qt; ++jt) {
        __syncthreads();
#pragma unroll
        for (int p = 0; p < 2; ++p) {
            int jr = p * 32 + (t >> 3);
            int ce = (t & 7) * 8;
            bf16x8 v = *(const bf16x8*)&Km[((size_t)b * S + (size_t)jt * 64 + jr) * D + hcol + ce];
            *(bf16x8*)&Ks[jr][ce] = v;
#pragma unroll
            for (int e = 0; e < 8; ++e) Vt[ce + e][jr] = v[e];
        }
        __syncthreads();

        f32x4 sv[4];
#pragma unroll
        for (int nt = 0; nt < 4; ++nt) {
            bf16x8 k0 = *(const bf16x8*)&Ks[nt * 16 + l15][quad * 8];
            bf16x8 k1 = *(const bf16x8*)&Ks[nt * 16 + l15][32 + quad * 8];
            f32x4 a = {0.f, 0.f, 0.f, 0.f};
            a = MFMA(qf0, k0, a);
            a = MFMA(qf1, k1, a);
            sv[nt] = a;
        }

#pragma unroll
        for (int nt = 0; nt < 4; ++nt)
#pragma unroll
            for (int r = 0; r < 4; ++r) {
                float s = scrub(sv[nt][r] * 0.125f, -1e30f, 1e30f);
                if (jt == qt && (jt * 64 + nt * 16 + l15) > (irow0 + r)) s = -1e30f;
                sv[nt][r] = s;
            }

        float mx[4], alpha[4], rsum[4];
#pragma unroll
        for (int r = 0; r < 4; ++r) {
            mx[r] = fmaxf(fmaxf(sv[0][r], sv[1][r]), fmaxf(sv[2][r], sv[3][r]));
#pragma unroll
            for (int off = 1; off < 16; off <<= 1)
                mx[r] = fmaxf(mx[r], __shfl_xor(mx[r], off));
            float mn = fmaxf(mrow[r], mx[r]);
            alpha[r] = __expf(mrow[r] - mn);
            mrow[r]  = mn;
            rsum[r]  = 0.f;
        }
#pragma unroll
        for (int nt = 0; nt < 4; ++nt)
#pragma unroll
            for (int r = 0; r < 4; ++r) {
                float p = __expf(sv[nt][r] - mrow[r]);
                sv[nt][r] = p;
                rsum[r] += p;
            }
#pragma unroll
        for (int r = 0; r < 4; ++r) {
#pragma unroll
            for (int off = 1; off < 16; off <<= 1)
                rsum[r] += __shfl_xor(rsum[r], off);
            lrow[r] = lrow[r] * alpha[r] + rsum[r];
        }
#pragma unroll
        for (int u = 0; u < 4; ++u)
#pragma unroll
            for (int r = 0; r < 4; ++r) accO[u][r] *= alpha[r];

#pragma unroll
        for (int nt = 0; nt < 4; ++nt)
#pragma unroll
            for (int r = 0; r < 4; ++r)
                Ps[wave * 16 + quad * 4 + r][nt * 16 + l15] = (bf16_t)sv[nt][r];
        __syncthreads();

        bf16x8 pa0 = *(const bf16x8*)&Ps[wave * 16 + l15][quad * 8];
        bf16x8 pa1 = *(const bf16x8*)&Ps[wave * 16 + l15][32 + quad * 8];
#pragma unroll
        for (int u = 0; u < 4; ++u) {
            bf16x8 v0 = *(const bf16x8*)&Vt[u * 16 + l15][quad * 8];
            bf16x8 v1 = *(const bf16x8*)&Vt[u * 16 + l15][32 + quad * 8];
            accO[u] = MFMA(pa0, v0, accO[u]);
            accO[u] = MFMA(pa1, v1, accO[u]);
        }
    }

    float invl[4];
#pragma unroll
    for (int r = 0; r < 4; ++r) invl[r] = 1.f / lrow[r];
#pragma unroll
    for (int u = 0; u < 4; ++u)
#pragma unroll
        for (int r = 0; r < 4; ++r)
            Oc[(qrow0 + wave * 16 + quad * 4 + r) * D + hcol + u * 16 + l15] =
                (bf16_t)(accO[u][r] * invl[r]);

    if (l15 == 0) {
        size_t base = ((size_t)(b * H + h)) * S + (size_t)qt * 64 + wave * 16 + quad * 4;
#pragma unroll
        for (int r = 0; r < 4; ++r) {
            m_ws[base + r]  = mrow[r];
            il_ws[base + r] = invl[r];
        }
    }
}

// ---------------------------------------------------------------------------
// Head-summed attention weights: out2[b,i,j] = sum_h exp(s*scale - m)/l (f32).
// ---------------------------------------------------------------------------
__global__ __launch_bounds__(256) void attn_wsum(
    const bf16_t* __restrict__ Q, const bf16_t* __restrict__ Km,
    const float* __restrict__ m_ws, const float* __restrict__ il_ws,
    float* __restrict__ out2)
{
    const int jt = blockIdx.x, qt = blockIdx.y, b = blockIdx.z;
    const int t  = threadIdx.x;
    float* tile = out2 + (size_t)b * S * S + (size_t)qt * 64 * S + (size_t)jt * 64;

    if (jt > qt) {
        int r0 = t >> 2, c0 = (t & 3) * 16;
#pragma unroll
        for (int e = 0; e < 16; ++e) tile[(size_t)r0 * S + c0 + e] = 0.f;
        return;
    }

    const int wave = t >> 6, lane = t & 63;
    const int quad = lane >> 4, l15 = lane & 15;
    __shared__ bf16_t Ks[64][72];
    __shared__ bf16_t Qs[64][72];

    for (int i = t; i < 64 * 72 / 2; i += 256) { ((int*)Ks)[i] = 0; ((int*)Qs)[i] = 0; }

    f32x4 accs[4];
#pragma unroll
    for (int nt = 0; nt < 4; ++nt) accs[nt] = {0.f, 0.f, 0.f, 0.f};

    for (int h = 0; h < H; ++h) {
        const int hcol = h * DK;
        __syncthreads();
#pragma unroll
        for (int p = 0; p < 2; ++p) {
            int jr = p * 32 + (t >> 3);
            int ce = (t & 7) * 8;
            *(bf16x8*)&Ks[jr][ce] =
                *(const bf16x8*)&Km[((size_t)b * S + (size_t)jt * 64 + jr) * D + hcol + ce];
            *(bf16x8*)&Qs[jr][ce] =
                *(const bf16x8*)&Q[((size_t)b * S + (size_t)qt * 64 + jr) * D + hcol + ce];
        }
        __syncthreads();

        bf16x8 qf0 = *(const bf16x8*)&Qs[wave * 16 + l15][quad * 8];
        bf16x8 qf1 = *(const bf16x8*)&Qs[wave * 16 + l15][32 + quad * 8];

        size_t mlb = ((size_t)(b * H + h)) * S + (size_t)qt * 64 + wave * 16 + quad * 4;
        float mr[4], il[4];
#pragma unroll
        for (int r = 0; r < 4; ++r) {
            mr[r] = scrub(m_ws[mlb + r], -1e30f, 1e30f);
            il[r] = scrub(il_ws[mlb + r], 0.f, 1e30f);
        }

#pragma unroll
        for (int nt = 0; nt < 4; ++nt) {
            bf16x8 k0 = *(const bf16x8*)&Ks[nt * 16 + l15][quad * 8];
            bf16x8 k1 = *(const bf16x8*)&Ks[nt * 16 + l15][32 + quad * 8];
            f32x4 a = {0.f, 0.f, 0.f, 0.f};
            a = MFMA(qf0, k0, a);
            a = MFMA(qf1, k1, a);
#pragma unroll
            for (int r = 0; r < 4; ++r) {
                int i = qt * 64 + wave * 16 + quad * 4 + r;
                int j = jt * 64 + nt * 16 + l15;
                float s = scrub(a[r] * 0.125f, -1e30f, 1e30f);
                float p = (j <= i) ? __expf(s - mr[r]) * il[r] : 0.f;
                accs[nt][r] += p;
            }
        }
    }

#pragma unroll
    for (int nt = 0; nt < 4; ++nt)
#pragma unroll
        for (int r = 0; r < 4; ++r)
            tile[(size_t)(wave * 16 + quad * 4 + r) * S + nt * 16 + l15] = accs[nt][r];
}

// ---------------------------------------------------------------------------
extern "C" void kernel_launch(void* const* d_in, const int* in_sizes, int n_in,
                              void* d_out, int out_size, void* d_ws, size_t ws_size,
                              hipStream_t stream)
{
    // Reference dtypes are float32 (threshold is bf16-tolerance mode, not
    // bf16 storage): all float tensors are f32 in global memory.
    const float* x    = (const float*)d_in[0];
    const float* z    = (const float*)d_in[1];
    // d_in[2] = causal mask (int32 tril) -- structure exploited directly
    const float* wq_w = (const float*)d_in[3];
    const float* wq_b = (const float*)d_in[4];
    const float* wk_w = (const float*)d_in[5];
    const float* wk_b = (const float*)d_in[6];
    // d_in[7], d_in[8] = wv (dead parameter: reference uses wk for V)
    const float* wo_w = (const float*)d_in[9];
    const float* wo_b = (const float*)d_in[10];

    float* out  = (float*)d_out;                    // chunk 0: [B,S,D] f32
    float* out2 = out + (size_t)Bsz * S * D;        // chunk 1: [B,S,S] f32

    // Workspace (16.5 MB): stats + internal bf16 Q,K. Concat (bf16) lives in
    // the out2 region (8 MB needed <= 32 MB there), consumed by the O-proj
    // GEMM before attn_wsum overwrites out2 last (same stream, sequential).
    float*  m_ws  = (float*)d_ws;
    float*  il_ws = m_ws + (size_t)Bsz * H * S;
    bf16_t* Qws   = (bf16_t*)(il_ws + (size_t)Bsz * H * S);
    bf16_t* Kws   = Qws + (size_t)Bsz * S * D;
    bf16_t* Cc    = (bf16_t*)out2;                  // concat scratch in d_out

    dim3 blk(256);
    gemm_bt<float, float, bf16_t>
        <<<dim3(D / 128, (Bsz * S) / 128, 1), blk, 0, stream>>>(x, wq_w, wq_b, Qws, Bsz * S, D, D);
    gemm_bt<float, float, bf16_t>
        <<<dim3(D / 128, (Bsz * S) / 128, 1), blk, 0, stream>>>(z, wk_w, wk_b, Kws, Bsz * S, D, D);
    attn_flash<<<dim3(S / 64, H, Bsz), blk, 0, stream>>>(Qws, Kws, Cc, m_ws, il_ws);
    gemm_bt<bf16_t, float, float>
        <<<dim3(D / 128, (Bsz * S) / 128, 1), blk, 0, stream>>>(Cc, wo_w, wo_b, out, Bsz * S, D, D);
    attn_wsum<<<dim3(S / 64, S / 64, Bsz), blk, 0, stream>>>(Qws, Kws, m_ws, il_ws, out2);
}

// Round 6
// 363.873 us; speedup vs baseline: 1.2587x; 1.2587x over previous
//
#include <hip/hip_runtime.h>

typedef __bf16 bf16_t;
typedef __bf16 bf16x4 __attribute__((ext_vector_type(4)));
typedef __bf16 bf16x8 __attribute__((ext_vector_type(8)));
typedef float  f32x4  __attribute__((ext_vector_type(4)));

#define MFMA(a, b, c) __builtin_amdgcn_mfma_f32_16x16x32_bf16((a), (b), (c), 0, 0, 0)

static constexpr int Bsz = 2, S = 2048, D = 1024, H = 16, DK = 64;

// load 8 contiguous elements as bf16x8 (converting if source is f32)
__device__ __forceinline__ bf16x8 ld8(const bf16_t* p) { return *(const bf16x8*)p; }
__device__ __forceinline__ bf16x8 ld8(const float* p) {
    float4 a = *(const float4*)p;
    float4 b = *(const float4*)(p + 4);
    bf16x8 r;
    r[0] = (bf16_t)a.x; r[1] = (bf16_t)a.y; r[2] = (bf16_t)a.z; r[3] = (bf16_t)a.w;
    r[4] = (bf16_t)b.x; r[5] = (bf16_t)b.y; r[6] = (bf16_t)b.z; r[7] = (bf16_t)b.w;
    return r;
}

// ---------------------------------------------------------------------------
// GEMM: C[M,N] = A[M,K] * B[N,K]^T + bias[N]; fp32 accum, bf16 MFMA.
// WRITE_KT=1 additionally writes C transposed per head: KT[b][h][d][s]
// (used by the K projection so flash attention needs no LDS transpose).
// ---------------------------------------------------------------------------
template <typename TA, typename TB, typename TC, int WRITE_KT>
__global__ __launch_bounds__(256) void gemm_bt(
    const TA* __restrict__ A, const TB* __restrict__ B,
    const float* __restrict__ bias, TC* __restrict__ C,
    bf16_t* __restrict__ KTout, int M, int N, int K)
{
    __shared__ bf16_t As[128][40];
    __shared__ bf16_t Bs[128][40];

    const int t    = threadIdx.x;
    const int wave = t >> 6, lane = t & 63;
    const int quad = lane >> 4, l15 = lane & 15;
    const int wm = (wave >> 1) * 64, wn = (wave & 1) * 64;
    const int rowbase = blockIdx.y * 128, colbase = blockIdx.x * 128;

    f32x4 acc[4][4];
#pragma unroll
    for (int i = 0; i < 4; ++i)
#pragma unroll
        for (int j = 0; j < 4; ++j) acc[i][j] = {0.f, 0.f, 0.f, 0.f};

    for (int kt = 0; kt < K; kt += 32) {
        __syncthreads();
#pragma unroll
        for (int c = 0; c < 2; ++c) {
            int f  = t + 256 * c;
            int r  = f >> 2;
            int cc = (f & 3) << 3;
            *(bf16x8*)&As[r][cc] = ld8(&A[(size_t)(rowbase + r) * K + kt + cc]);
            *(bf16x8*)&Bs[r][cc] = ld8(&B[(size_t)(colbase + r) * K + kt + cc]);
        }
        __syncthreads();

        bf16x8 af[4], bfr[4];
#pragma unroll
        for (int mt = 0; mt < 4; ++mt)
            af[mt] = *(const bf16x8*)&As[wm + mt * 16 + l15][quad * 8];
#pragma unroll
        for (int nt = 0; nt < 4; ++nt)
            bfr[nt] = *(const bf16x8*)&Bs[wn + nt * 16 + l15][quad * 8];
#pragma unroll
        for (int mt = 0; mt < 4; ++mt)
#pragma unroll
            for (int nt = 0; nt < 4; ++nt)
                acc[mt][nt] = MFMA(af[mt], bfr[nt], acc[mt][nt]);
    }

#pragma unroll
    for (int nt = 0; nt < 4; ++nt) {
        int col  = colbase + wn + nt * 16 + l15;
        float bv = bias[col];
#pragma unroll
        for (int mt = 0; mt < 4; ++mt) {
            int row0 = rowbase + wm + mt * 16 + quad * 4;
#pragma unroll
            for (int r = 0; r < 4; ++r) {
                float v = acc[mt][nt][r] + bv;
                C[(size_t)(row0 + r) * N + col] = (TC)v;
                if (WRITE_KT) {
                    int row = row0 + r;                    // b*S + s
                    int bb = row >> 11, srow = row & (S - 1);
                    int hh = col >> 6,  dd   = col & 63;
                    KTout[(((size_t)bb * H + hh) * DK + dd) * S + srow] = (bf16_t)v;
                }
            }
        }
    }
}

// ---------------------------------------------------------------------------
// Flash attention (causal, V == K), S^T formulation — no LDS transposes.
// Block = (qt-pair, h, b); each block runs qt = x and qt = 31-x (33 iters,
// perfectly balanced). Wave owns 16 q-rows. Writes O (bf16 concat layout)
// and per-row (m, 1/l) stats.
// ---------------------------------------------------------------------------
__global__ __launch_bounds__(256) void attn_flash(
    const bf16_t* __restrict__ Q, const bf16_t* __restrict__ Km,
    const bf16_t* __restrict__ KT,
    bf16_t* __restrict__ Oc, float* __restrict__ m_ws, float* __restrict__ il_ws)
{
    const int h = blockIdx.y, b = blockIdx.z;
    const int t = threadIdx.x;
    const int wave = t >> 6, lane = t & 63;
    const int quad = lane >> 4, l15 = lane & 15;

    __shared__ bf16_t Ks[64][72];    // K tile  [j][d]
    __shared__ bf16_t KTs[64][72];   // K^T tile [d][j]  (= V^T, since V==K)
    __shared__ bf16_t PQ[64][72];    // Q staging, then per-wave P strips

    const int hcol = h * DK;
    const bf16_t* KTh = KT + ((size_t)(b * H + h)) * DK * S;

    for (int half = 0; half < 2; ++half) {
        const int qt = half == 0 ? (int)blockIdx.x : 31 - (int)blockIdx.x;
        const size_t qrow0 = (size_t)b * S + (size_t)qt * 64;

        __syncthreads();   // PQ reuse across halves
#pragma unroll
        for (int p = 0; p < 2; ++p) {
            int jr = p * 32 + (t >> 3), ce = (t & 7) * 8;
            *(bf16x8*)&PQ[jr][ce] = *(const bf16x8*)&Q[(qrow0 + jr) * D + hcol + ce];
        }
        __syncthreads();
        const bf16x8 qf0 = *(const bf16x8*)&PQ[wave * 16 + l15][quad * 8];
        const bf16x8 qf1 = *(const bf16x8*)&PQ[wave * 16 + l15][32 + quad * 8];

        f32x4 accO[4];
#pragma unroll
        for (int u = 0; u < 4; ++u) accO[u] = {0.f, 0.f, 0.f, 0.f};
        // per-lane softmax state for i = qt*64 + wave*16 + l15 (replicated /quad)
        float m_cur = -1e30f, l_cur = 0.f;

        for (int jt = 0; jt <= qt; ++jt) {
            __syncthreads();
#pragma unroll
            for (int p = 0; p < 2; ++p) {
                int jr = p * 32 + (t >> 3), ce = (t & 7) * 8;
                *(bf16x8*)&Ks[jr][ce] =
                    *(const bf16x8*)&Km[((size_t)b * S + (size_t)jt * 64 + jr) * D + hcol + ce];
                *(bf16x8*)&KTs[jr][ce] =
                    *(const bf16x8*)&KTh[(size_t)jr * S + (size_t)jt * 64 + ce];
            }
            __syncthreads();

            // S^T tile: rows j (nt*16+quad*4+r), cols i (l15). A=K, B=Q.
            f32x4 sv[4];
#pragma unroll
            for (int nt = 0; nt < 4; ++nt) {
                bf16x8 a0 = *(const bf16x8*)&Ks[nt * 16 + l15][quad * 8];
                bf16x8 a1 = *(const bf16x8*)&Ks[nt * 16 + l15][32 + quad * 8];
                f32x4 a = {0.f, 0.f, 0.f, 0.f};
                a = MFMA(a0, qf0, a);
                a = MFMA(a1, qf1, a);
                sv[nt] = a;
            }

            const bool diag = (jt == qt);
            const int iloc = wave * 16 + l15;   // q-row local index (0..63)
#pragma unroll
            for (int nt = 0; nt < 4; ++nt)
#pragma unroll
                for (int r = 0; r < 4; ++r) {
                    float s = sv[nt][r] * 0.125f;
                    // R5 BUG: compared j_loc (0..63) vs l15 (0..15) -> waves
                    // 1-3 over-masked. i local index is wave*16 + l15.
                    if (diag && (nt * 16 + quad * 4 + r) > iloc) s = -1e30f;
                    sv[nt][r] = s;
                }

            // online softmax: 16 local values + 2 cross-quad shuffles
            float tm = sv[0][0];
#pragma unroll
            for (int nt = 0; nt < 4; ++nt)
#pragma unroll
                for (int r = 0; r < 4; ++r) tm = fmaxf(tm, sv[nt][r]);
            tm = fmaxf(tm, __shfl_xor(tm, 16));
            tm = fmaxf(tm, __shfl_xor(tm, 32));
            float m_new = fmaxf(m_cur, tm);
            float alpha = __expf(m_cur - m_new);
            m_cur = m_new;
            float rs = 0.f;
#pragma unroll
            for (int nt = 0; nt < 4; ++nt)
#pragma unroll
                for (int r = 0; r < 4; ++r) {
                    float p = __expf(sv[nt][r] - m_new);
                    sv[nt][r] = p;
                    rs += p;
                }
            rs += __shfl_xor(rs, 16);
            rs += __shfl_xor(rs, 32);
            l_cur = l_cur * alpha + rs;

            // alpha for output-row index i_loc = quad*4+r lives at lane l15=i_loc
            float alpha4[4];
#pragma unroll
            for (int r = 0; r < 4; ++r)
                alpha4[r] = __shfl(alpha, (quad << 4) + quad * 4 + r, 64);
#pragma unroll
            for (int u = 0; u < 4; ++u)
#pragma unroll
                for (int r = 0; r < 4; ++r) accO[u][r] *= alpha4[r];

            // P^T regs -> P row-major strip (wave-private): 4x ds_write_b64
#pragma unroll
            for (int nt = 0; nt < 4; ++nt) {
                bf16x4 pk;
                pk[0] = (bf16_t)sv[nt][0]; pk[1] = (bf16_t)sv[nt][1];
                pk[2] = (bf16_t)sv[nt][2]; pk[3] = (bf16_t)sv[nt][3];
                *(bf16x4*)&PQ[wave * 16 + l15][nt * 16 + quad * 4] = pk;
            }
            // strips are wave-private: drain this wave's DS writes, no barrier
            asm volatile("s_waitcnt lgkmcnt(0)" ::: "memory");

            bf16x8 pa0 = *(const bf16x8*)&PQ[wave * 16 + l15][quad * 8];
            bf16x8 pa1 = *(const bf16x8*)&PQ[wave * 16 + l15][32 + quad * 8];
#pragma unroll
            for (int u = 0; u < 4; ++u) {
                bf16x8 v0 = *(const bf16x8*)&KTs[u * 16 + l15][quad * 8];
                bf16x8 v1 = *(const bf16x8*)&KTs[u * 16 + l15][32 + quad * 8];
                accO[u] = MFMA(pa0, v0, accO[u]);
                accO[u] = MFMA(pa1, v1, accO[u]);
            }
        }

        float invl = 1.f / l_cur;
        float invl4[4];
#pragma unroll
        for (int r = 0; r < 4; ++r)
            invl4[r] = __shfl(invl, (quad << 4) + quad * 4 + r, 64);
#pragma unroll
        for (int u = 0; u < 4; ++u)
#pragma unroll
            for (int r = 0; r < 4; ++r)
                Oc[(qrow0 + wave * 16 + quad * 4 + r) * D + hcol + u * 16 + l15] =
                    (bf16_t)(accO[u][r] * invl4[r]);

        if (quad == 0) {
            size_t sb = ((size_t)(b * H + h)) * S + (size_t)qt * 64 + wave * 16 + l15;
            m_ws[sb]  = m_cur;
            il_ws[sb] = invl;
        }
    }
}

// ---------------------------------------------------------------------------
// Head-summed attention weights: out2[b,i,j] = sum_h exp(s*scale - m)/l (f32).
// 2 heads per staging round (8 rounds -> half the barriers).
// ---------------------------------------------------------------------------
__global__ __launch_bounds__(256) void attn_wsum(
    const bf16_t* __restrict__ Q, const bf16_t* __restrict__ Km,
    const float* __restrict__ m_ws, const float* __restrict__ il_ws,
    float* __restrict__ out2)
{
    const int jt = blockIdx.x, qt = blockIdx.y, b = blockIdx.z;
    const int t  = threadIdx.x;
    float* tile = out2 + (size_t)b * S * S + (size_t)qt * 64 * S + (size_t)jt * 64;

    if (jt > qt) {
        int r0 = t >> 2, c0 = (t & 3) * 16;
#pragma unroll
        for (int e = 0; e < 16; ++e) tile[(size_t)r0 * S + c0 + e] = 0.f;
        return;
    }

    const int wave = t >> 6, lane = t & 63;
    const int quad = lane >> 4, l15 = lane & 15;
    __shared__ bf16_t Ks2[2][64][72];
    __shared__ bf16_t Qs2[2][64][72];

    f32x4 accs[4];
#pragma unroll
    for (int nt = 0; nt < 4; ++nt) accs[nt] = {0.f, 0.f, 0.f, 0.f};

    for (int hr = 0; hr < H / 2; ++hr) {
        __syncthreads();
#pragma unroll
        for (int p = 0; p < 2; ++p) {
            int jr = p * 32 + (t >> 3), ce = (t & 7) * 8;
#pragma unroll
            for (int hh = 0; hh < 2; ++hh) {
                int hc = (hr * 2 + hh) * DK;
                *(bf16x8*)&Ks2[hh][jr][ce] =
                    *(const bf16x8*)&Km[((size_t)b * S + (size_t)jt * 64 + jr) * D + hc + ce];
                *(bf16x8*)&Qs2[hh][jr][ce] =
                    *(const bf16x8*)&Q[((size_t)b * S + (size_t)qt * 64 + jr) * D + hc + ce];
            }
        }
        __syncthreads();

#pragma unroll
        for (int hh = 0; hh < 2; ++hh) {
            const int h = hr * 2 + hh;
            bf16x8 qf0 = *(const bf16x8*)&Qs2[hh][wave * 16 + l15][quad * 8];
            bf16x8 qf1 = *(const bf16x8*)&Qs2[hh][wave * 16 + l15][32 + quad * 8];

            size_t mlb = ((size_t)(b * H + h)) * S + (size_t)qt * 64 + wave * 16 + quad * 4;
            f32x4 mr = *(const f32x4*)&m_ws[mlb];
            f32x4 il = *(const f32x4*)&il_ws[mlb];

#pragma unroll
            for (int nt = 0; nt < 4; ++nt) {
                bf16x8 k0 = *(const bf16x8*)&Ks2[hh][nt * 16 + l15][quad * 8];
                bf16x8 k1 = *(const bf16x8*)&Ks2[hh][nt * 16 + l15][32 + quad * 8];
                f32x4 a = {0.f, 0.f, 0.f, 0.f};
                a = MFMA(qf0, k0, a);
                a = MFMA(qf1, k1, a);
#pragma unroll
                for (int r = 0; r < 4; ++r) {
                    int i = qt * 64 + wave * 16 + quad * 4 + r;
                    int j = jt * 64 + nt * 16 + l15;
                    float p = (j <= i) ? __expf(a[r] * 0.125f - mr[r]) * il[r] : 0.f;
                    accs[nt][r] += p;
                }
            }
        }
    }

#pragma unroll
    for (int nt = 0; nt < 4; ++nt)
#pragma unroll
        for (int r = 0; r < 4; ++r)
            tile[(size_t)(wave * 16 + quad * 4 + r) * S + nt * 16 + l15] = accs[nt][r];
}

// ---------------------------------------------------------------------------
extern "C" void kernel_launch(void* const* d_in, const int* in_sizes, int n_in,
                              void* d_out, int out_size, void* d_ws, size_t ws_size,
                              hipStream_t stream)
{
    const float* x    = (const float*)d_in[0];
    const float* z    = (const float*)d_in[1];
    // d_in[2] = causal mask (int32 tril) -- structure exploited directly
    const float* wq_w = (const float*)d_in[3];
    const float* wq_b = (const float*)d_in[4];
    const float* wk_w = (const float*)d_in[5];
    const float* wk_b = (const float*)d_in[6];
    // d_in[7], d_in[8] = wv (dead parameter: reference uses wk for V)
    const float* wo_w = (const float*)d_in[9];
    const float* wo_b = (const float*)d_in[10];

    float* out  = (float*)d_out;                    // chunk 0: [B,S,D] f32
    float* out2 = out + (size_t)Bsz * S * D;        // chunk 1: [B,S,S] f32 (32 MB)

    // Workspace (16.5 MB): stats + internal bf16 Q,K.
    float*  m_ws  = (float*)d_ws;
    float*  il_ws = m_ws + (size_t)Bsz * H * S;
    bf16_t* Qws   = (bf16_t*)(il_ws + (size_t)Bsz * H * S);
    bf16_t* Kws   = Qws + (size_t)Bsz * S * D;
    // Scratch parked inside out2's 32 MB (both dead before attn_wsum runs):
    bf16_t* Cc    = (bf16_t*)out2;                  // concat  [B*S, D]  (8 MB)
    bf16_t* KTws  = Cc + (size_t)Bsz * S * D;       // K^T [B,H,DK,S]    (8 MB)

    dim3 blk(256);
    gemm_bt<float, float, bf16_t, 0>
        <<<dim3(D / 128, (Bsz * S) / 128, 1), blk, 0, stream>>>(
            x, wq_w, wq_b, Qws, nullptr, Bsz * S, D, D);
    gemm_bt<float, float, bf16_t, 1>
        <<<dim3(D / 128, (Bsz * S) / 128, 1), blk, 0, stream>>>(
            z, wk_w, wk_b, Kws, KTws, Bsz * S, D, D);
    attn_flash<<<dim3(S / 128, H, Bsz), blk, 0, stream>>>(
        Qws, Kws, KTws, Cc, m_ws, il_ws);
    gemm_bt<bf16_t, float, float, 0>
        <<<dim3(D / 128, (Bsz * S) / 128, 1), blk, 0, stream>>>(
            Cc, wo_w, wo_b, out, nullptr, Bsz * S, D, D);
    attn_wsum<<<dim3(S / 64, S / 64, Bsz), blk, 0, stream>>>(
        Qws, Kws, m_ws, il_ws, out2);
}

// Round 7
// 325.909 us; speedup vs baseline: 1.4054x; 1.1165x over previous
//
#include <hip/hip_runtime.h>

typedef __bf16 bf16_t;
typedef __bf16 bf16x4 __attribute__((ext_vector_type(4)));
typedef __bf16 bf16x8 __attribute__((ext_vector_type(8)));
typedef float  f32x4  __attribute__((ext_vector_type(4)));

#define MFMA(a, b, c) __builtin_amdgcn_mfma_f32_16x16x32_bf16((a), (b), (c), 0, 0, 0)

static constexpr int Bsz = 2, S = 2048, D = 1024, H = 16, DK = 64;

// load 8 contiguous elements as bf16x8 (converting if source is f32)
__device__ __forceinline__ bf16x8 ld8(const bf16_t* p) { return *(const bf16x8*)p; }
__device__ __forceinline__ bf16x8 ld8(const float* p) {
    float4 a = *(const float4*)p;
    float4 b = *(const float4*)(p + 4);
    bf16x8 r;
    r[0] = (bf16_t)a.x; r[1] = (bf16_t)a.y; r[2] = (bf16_t)a.z; r[3] = (bf16_t)a.w;
    r[4] = (bf16_t)b.x; r[5] = (bf16_t)b.y; r[6] = (bf16_t)b.z; r[7] = (bf16_t)b.w;
    return r;
}

// ---------------------------------------------------------------------------
// GEMM: C[M,N] = A[M,K] * B[N,K]^T + bias[N]; fp32 accum, bf16 MFMA.
// WRITE_KT=1 additionally writes C transposed per head: KT[b][h][d][s].
// ---------------------------------------------------------------------------
template <typename TA, typename TB, typename TC, int WRITE_KT>
__global__ __launch_bounds__(256) void gemm_bt(
    const TA* __restrict__ A, const TB* __restrict__ B,
    const float* __restrict__ bias, TC* __restrict__ C,
    bf16_t* __restrict__ KTout, int M, int N, int K)
{
    __shared__ bf16_t As[128][40];
    __shared__ bf16_t Bs[128][40];

    const int t    = threadIdx.x;
    const int wave = t >> 6, lane = t & 63;
    const int quad = lane >> 4, l15 = lane & 15;
    const int wm = (wave >> 1) * 64, wn = (wave & 1) * 64;
    const int rowbase = blockIdx.y * 128, colbase = blockIdx.x * 128;

    f32x4 acc[4][4];
#pragma unroll
    for (int i = 0; i < 4; ++i)
#pragma unroll
        for (int j = 0; j < 4; ++j) acc[i][j] = {0.f, 0.f, 0.f, 0.f};

    for (int kt = 0; kt < K; kt += 32) {
        __syncthreads();
#pragma unroll
        for (int c = 0; c < 2; ++c) {
            int f  = t + 256 * c;
            int r  = f >> 2;
            int cc = (f & 3) << 3;
            *(bf16x8*)&As[r][cc] = ld8(&A[(size_t)(rowbase + r) * K + kt + cc]);
            *(bf16x8*)&Bs[r][cc] = ld8(&B[(size_t)(colbase + r) * K + kt + cc]);
        }
        __syncthreads();

        bf16x8 af[4], bfr[4];
#pragma unroll
        for (int mt = 0; mt < 4; ++mt)
            af[mt] = *(const bf16x8*)&As[wm + mt * 16 + l15][quad * 8];
#pragma unroll
        for (int nt = 0; nt < 4; ++nt)
            bfr[nt] = *(const bf16x8*)&Bs[wn + nt * 16 + l15][quad * 8];
#pragma unroll
        for (int mt = 0; mt < 4; ++mt)
#pragma unroll
            for (int nt = 0; nt < 4; ++nt)
                acc[mt][nt] = MFMA(af[mt], bfr[nt], acc[mt][nt]);
    }

#pragma unroll
    for (int nt = 0; nt < 4; ++nt) {
        int col  = colbase + wn + nt * 16 + l15;
        float bv = bias[col];
#pragma unroll
        for (int mt = 0; mt < 4; ++mt) {
            int row0 = rowbase + wm + mt * 16 + quad * 4;
#pragma unroll
            for (int r = 0; r < 4; ++r) {
                float v = acc[mt][nt][r] + bv;
                C[(size_t)(row0 + r) * N + col] = (TC)v;
                if (WRITE_KT) {
                    int row = row0 + r;                    // b*S + s
                    int bb = row >> 11, srow = row & (S - 1);
                    int hh = col >> 6,  dd   = col & 63;
                    KTout[(((size_t)bb * H + hh) * DK + dd) * S + srow] = (bf16_t)v;
                }
            }
        }
    }
}

// ---------------------------------------------------------------------------
// Flash attention (causal, V == K), S^T formulation, software-pipelined:
// global loads for tile jt+1 issued before compute on tile jt (LDS dbuf),
// ONE barrier per iteration (stores@j and reads@j touch disjoint buffers;
// stores@j vs reads@j-1 of the same buffer are separated by barrier@j-1).
// ---------------------------------------------------------------------------
__global__ __launch_bounds__(256) void attn_flash(
    const bf16_t* __restrict__ Q, const bf16_t* __restrict__ Km,
    const bf16_t* __restrict__ KT,
    bf16_t* __restrict__ Oc, float* __restrict__ m_ws, float* __restrict__ il_ws)
{
    const int h = blockIdx.y, b = blockIdx.z;
    const int t = threadIdx.x;
    const int wave = t >> 6, lane = t & 63;
    const int quad = lane >> 4, l15 = lane & 15;

    __shared__ bf16_t Ks[2][64][72];    // K tiles  [j][d], double-buffered
    __shared__ bf16_t KTs[2][64][72];   // K^T tiles [d][j] (= V^T)
    __shared__ bf16_t PQ[64][72];       // Q staging, then per-wave P strips

    const int hcol = h * DK;
    const bf16_t* KTh = KT + ((size_t)(b * H + h)) * DK * S;
    const size_t bS = (size_t)b * S;

    const int jr = (t >> 3);            // 0..31 (staging row, +p*32)
    const int ce = (t & 7) * 8;         // staging col element

    for (int half = 0; half < 2; ++half) {
        const int qt = half == 0 ? (int)blockIdx.x : 31 - (int)blockIdx.x;
        const size_t qrow0 = bS + (size_t)qt * 64;

        // ---- prologue: issue Q loads + jt=0 tile loads, stage both, ONE barrier
        __syncthreads();   // PQ/buf0 reuse vs previous half's reads
        bf16x8 qld[2], kreg[2], ktreg[2];
#pragma unroll
        for (int p = 0; p < 2; ++p) {
            qld[p]   = *(const bf16x8*)&Q[(qrow0 + p * 32 + jr) * D + hcol + ce];
            kreg[p]  = *(const bf16x8*)&Km[(bS + p * 32 + jr) * D + hcol + ce];
            ktreg[p] = *(const bf16x8*)&KTh[(size_t)(p * 32 + jr) * S + ce];
        }
#pragma unroll
        for (int p = 0; p < 2; ++p) {
            *(bf16x8*)&PQ[p * 32 + jr][ce]       = qld[p];
            *(bf16x8*)&Ks[0][p * 32 + jr][ce]    = kreg[p];
            *(bf16x8*)&KTs[0][p * 32 + jr][ce]   = ktreg[p];
        }
        __syncthreads();
        const bf16x8 qf0 = *(const bf16x8*)&PQ[wave * 16 + l15][quad * 8];
        const bf16x8 qf1 = *(const bf16x8*)&PQ[wave * 16 + l15][32 + quad * 8];

        f32x4 accO[4];
#pragma unroll
        for (int u = 0; u < 4; ++u) accO[u] = {0.f, 0.f, 0.f, 0.f};
        float m_cur = -1e30f, l_cur = 0.f;

        const int iloc = wave * 16 + l15;   // q-row local index (0..63)

        for (int jt = 0; jt <= qt; ++jt) {
            const int cur = jt & 1, nxt = cur ^ 1;

            // ---- prefetch next tile into regs (latency hidden under compute)
            if (jt < qt) {
#pragma unroll
                for (int p = 0; p < 2; ++p) {
                    kreg[p]  = *(const bf16x8*)&Km[(bS + (size_t)(jt + 1) * 64 + p * 32 + jr) * D + hcol + ce];
                    ktreg[p] = *(const bf16x8*)&KTh[(size_t)(p * 32 + jr) * S + (size_t)(jt + 1) * 64 + ce];
                }
            }

            // ---- compute on buf[cur]
            f32x4 sv[4];
#pragma unroll
            for (int nt = 0; nt < 4; ++nt) {
                bf16x8 a0 = *(const bf16x8*)&Ks[cur][nt * 16 + l15][quad * 8];
                bf16x8 a1 = *(const bf16x8*)&Ks[cur][nt * 16 + l15][32 + quad * 8];
                f32x4 a = {0.f, 0.f, 0.f, 0.f};
                a = MFMA(a0, qf0, a);
                a = MFMA(a1, qf1, a);
                sv[nt] = a;
            }

            const bool diag = (jt == qt);
#pragma unroll
            for (int nt = 0; nt < 4; ++nt)
#pragma unroll
                for (int r = 0; r < 4; ++r) {
                    float s = sv[nt][r] * 0.125f;
                    if (diag && (nt * 16 + quad * 4 + r) > iloc) s = -1e30f;
                    sv[nt][r] = s;
                }

            float tm = sv[0][0];
#pragma unroll
            for (int nt = 0; nt < 4; ++nt)
#pragma unroll
                for (int r = 0; r < 4; ++r) tm = fmaxf(tm, sv[nt][r]);
            tm = fmaxf(tm, __shfl_xor(tm, 16));
            tm = fmaxf(tm, __shfl_xor(tm, 32));
            float m_new = fmaxf(m_cur, tm);
            float alpha = __expf(m_cur - m_new);
            m_cur = m_new;
            float rs = 0.f;
#pragma unroll
            for (int nt = 0; nt < 4; ++nt)
#pragma unroll
                for (int r = 0; r < 4; ++r) {
                    float p = __expf(sv[nt][r] - m_new);
                    sv[nt][r] = p;
                    rs += p;
                }
            rs += __shfl_xor(rs, 16);
            rs += __shfl_xor(rs, 32);
            l_cur = l_cur * alpha + rs;

            float alpha4[4];
#pragma unroll
            for (int r = 0; r < 4; ++r)
                alpha4[r] = __shfl(alpha, (quad << 4) + quad * 4 + r, 64);
#pragma unroll
            for (int u = 0; u < 4; ++u)
#pragma unroll
                for (int r = 0; r < 4; ++r) accO[u][r] *= alpha4[r];

            // P^T regs -> P row-major strip (wave-private): 4x ds_write_b64
#pragma unroll
            for (int nt = 0; nt < 4; ++nt) {
                bf16x4 pk;
                pk[0] = (bf16_t)sv[nt][0]; pk[1] = (bf16_t)sv[nt][1];
                pk[2] = (bf16_t)sv[nt][2]; pk[3] = (bf16_t)sv[nt][3];
                *(bf16x4*)&PQ[wave * 16 + l15][nt * 16 + quad * 4] = pk;
            }
            asm volatile("s_waitcnt lgkmcnt(0)" ::: "memory");  // wave-private drain

            bf16x8 pa0 = *(const bf16x8*)&PQ[wave * 16 + l15][quad * 8];
            bf16x8 pa1 = *(const bf16x8*)&PQ[wave * 16 + l15][32 + quad * 8];
#pragma unroll
            for (int u = 0; u < 4; ++u) {
                bf16x8 v0 = *(const bf16x8*)&KTs[cur][u * 16 + l15][quad * 8];
                bf16x8 v1 = *(const bf16x8*)&KTs[cur][u * 16 + l15][32 + quad * 8];
                accO[u] = MFMA(pa0, v0, accO[u]);
                accO[u] = MFMA(pa1, v1, accO[u]);
            }

            // ---- write prefetched tile into buf[nxt], single barrier
            if (jt < qt) {
#pragma unroll
                for (int p = 0; p < 2; ++p) {
                    *(bf16x8*)&Ks[nxt][p * 32 + jr][ce]  = kreg[p];
                    *(bf16x8*)&KTs[nxt][p * 32 + jr][ce] = ktreg[p];
                }
            }
            __syncthreads();
        }

        float invl = 1.f / l_cur;
        float invl4[4];
#pragma unroll
        for (int r = 0; r < 4; ++r)
            invl4[r] = __shfl(invl, (quad << 4) + quad * 4 + r, 64);
#pragma unroll
        for (int u = 0; u < 4; ++u)
#pragma unroll
            for (int r = 0; r < 4; ++r)
                Oc[(qrow0 + wave * 16 + quad * 4 + r) * D + hcol + u * 16 + l15] =
                    (bf16_t)(accO[u][r] * invl4[r]);

        if (quad == 0) {
            size_t sb = ((size_t)(b * H + h)) * S + (size_t)qt * 64 + wave * 16 + l15;
            m_ws[sb]  = m_cur;
            il_ws[sb] = invl;
        }
    }
}

// ---------------------------------------------------------------------------
// Head-summed attention weights: out2[b,i,j] = sum_h exp(s*scale - m)/l (f32).
// Software-pipelined: prefetch head h+1 tiles during compute on h (LDS dbuf,
// one barrier per head).
// ---------------------------------------------------------------------------
__global__ __launch_bounds__(256) void attn_wsum(
    const bf16_t* __restrict__ Q, const bf16_t* __restrict__ Km,
    const float* __restrict__ m_ws, const float* __restrict__ il_ws,
    float* __restrict__ out2)
{
    const int jt = blockIdx.x, qt = blockIdx.y, b = blockIdx.z;
    const int t  = threadIdx.x;
    float* tile = out2 + (size_t)b * S * S + (size_t)qt * 64 * S + (size_t)jt * 64;

    if (jt > qt) {
        int r0 = t >> 2, c0 = (t & 3) * 16;
#pragma unroll
        for (int e = 0; e < 16; ++e) tile[(size_t)r0 * S + c0 + e] = 0.f;
        return;
    }

    const int wave = t >> 6, lane = t & 63;
    const int quad = lane >> 4, l15 = lane & 15;
    __shared__ bf16_t Ks[2][64][72];
    __shared__ bf16_t Qs[2][64][72];

    const int jr = (t >> 3), ce = (t & 7) * 8;
    const size_t krow = (size_t)b * S + (size_t)jt * 64;
    const size_t qrow = (size_t)b * S + (size_t)qt * 64;

    f32x4 accs[4];
#pragma unroll
    for (int nt = 0; nt < 4; ++nt) accs[nt] = {0.f, 0.f, 0.f, 0.f};

    // prologue: load + stage head 0, one barrier
    bf16x8 kreg[2], qreg[2];
#pragma unroll
    for (int p = 0; p < 2; ++p) {
        kreg[p] = *(const bf16x8*)&Km[(krow + p * 32 + jr) * D + ce];
        qreg[p] = *(const bf16x8*)&Q[(qrow + p * 32 + jr) * D + ce];
    }
#pragma unroll
    for (int p = 0; p < 2; ++p) {
        *(bf16x8*)&Ks[0][p * 32 + jr][ce] = kreg[p];
        *(bf16x8*)&Qs[0][p * 32 + jr][ce] = qreg[p];
    }
    __syncthreads();

    for (int h = 0; h < H; ++h) {
        const int cur = h & 1, nxt = cur ^ 1;

        if (h < H - 1) {
            const int hc = (h + 1) * DK;
#pragma unroll
            for (int p = 0; p < 2; ++p) {
                kreg[p] = *(const bf16x8*)&Km[(krow + p * 32 + jr) * D + hc + ce];
                qreg[p] = *(const bf16x8*)&Q[(qrow + p * 32 + jr) * D + hc + ce];
            }
        }

        bf16x8 qf0 = *(const bf16x8*)&Qs[cur][wave * 16 + l15][quad * 8];
        bf16x8 qf1 = *(const bf16x8*)&Qs[cur][wave * 16 + l15][32 + quad * 8];

        size_t mlb = ((size_t)(b * H + h)) * S + (size_t)qt * 64 + wave * 16 + quad * 4;
        f32x4 mr = *(const f32x4*)&m_ws[mlb];
        f32x4 il = *(const f32x4*)&il_ws[mlb];

#pragma unroll
        for (int nt = 0; nt < 4; ++nt) {
            bf16x8 k0 = *(const bf16x8*)&Ks[cur][nt * 16 + l15][quad * 8];
            bf16x8 k1 = *(const bf16x8*)&Ks[cur][nt * 16 + l15][32 + quad * 8];
            f32x4 a = {0.f, 0.f, 0.f, 0.f};
            a = MFMA(qf0, k0, a);
            a = MFMA(qf1, k1, a);
#pragma unroll
            for (int r = 0; r < 4; ++r) {
                int i = qt * 64 + wave * 16 + quad * 4 + r;
                int j = jt * 64 + nt * 16 + l15;
                float p = (j <= i) ? __expf(a[r] * 0.125f - mr[r]) * il[r] : 0.f;
                accs[nt][r] += p;
            }
        }

        if (h < H - 1) {
#pragma unroll
            for (int p = 0; p < 2; ++p) {
                *(bf16x8*)&Ks[nxt][p * 32 + jr][ce] = kreg[p];
                *(bf16x8*)&Qs[nxt][p * 32 + jr][ce] = qreg[p];
            }
        }
        __syncthreads();
    }

#pragma unroll
    for (int nt = 0; nt < 4; ++nt)
#pragma unroll
        for (int r = 0; r < 4; ++r)
            tile[(size_t)(wave * 16 + quad * 4 + r) * S + nt * 16 + l15] = accs[nt][r];
}

// ---------------------------------------------------------------------------
extern "C" void kernel_launch(void* const* d_in, const int* in_sizes, int n_in,
                              void* d_out, int out_size, void* d_ws, size_t ws_size,
                              hipStream_t stream)
{
    const float* x    = (const float*)d_in[0];
    const float* z    = (const float*)d_in[1];
    // d_in[2] = causal mask (int32 tril) -- structure exploited directly
    const float* wq_w = (const float*)d_in[3];
    const float* wq_b = (const float*)d_in[4];
    const float* wk_w = (const float*)d_in[5];
    const float* wk_b = (const float*)d_in[6];
    // d_in[7], d_in[8] = wv (dead parameter: reference uses wk for V)
    const float* wo_w = (const float*)d_in[9];
    const float* wo_b = (const float*)d_in[10];

    float* out  = (float*)d_out;                    // chunk 0: [B,S,D] f32
    float* out2 = out + (size_t)Bsz * S * D;        // chunk 1: [B,S,S] f32 (32 MB)

    // Workspace (16.5 MB): stats + internal bf16 Q,K.
    float*  m_ws  = (float*)d_ws;
    float*  il_ws = m_ws + (size_t)Bsz * H * S;
    bf16_t* Qws   = (bf16_t*)(il_ws + (size_t)Bsz * H * S);
    bf16_t* Kws   = Qws + (size_t)Bsz * S * D;
    // Scratch parked inside out2's 32 MB (both dead before attn_wsum runs):
    bf16_t* Cc    = (bf16_t*)out2;                  // concat  [B*S, D]  (8 MB)
    bf16_t* KTws  = Cc + (size_t)Bsz * S * D;       // K^T [B,H,DK,S]    (8 MB)

    dim3 blk(256);
    gemm_bt<float, float, bf16_t, 0>
        <<<dim3(D / 128, (Bsz * S) / 128, 1), blk, 0, stream>>>(
            x, wq_w, wq_b, Qws, nullptr, Bsz * S, D, D);
    gemm_bt<float, float, bf16_t, 1>
        <<<dim3(D / 128, (Bsz * S) / 128, 1), blk, 0, stream>>>(
            z, wk_w, wk_b, Kws, KTws, Bsz * S, D, D);
    attn_flash<<<dim3(S / 128, H, Bsz), blk, 0, stream>>>(
        Qws, Kws, KTws, Cc, m_ws, il_ws);
    gemm_bt<bf16_t, float, float, 0>
        <<<dim3(D / 128, (Bsz * S) / 128, 1), blk, 0, stream>>>(
            Cc, wo_w, wo_b, out, nullptr, Bsz * S, D, D);
    attn_wsum<<<dim3(S / 64, S / 64, Bsz), blk, 0, stream>>>(
        Qws, Kws, m_ws, il_ws, out2);
}

// Round 8
// 286.775 us; speedup vs baseline: 1.5971x; 1.1365x over previous
//
#include <hip/hip_runtime.h>

typedef __bf16 bf16_t;
typedef __bf16 bf16x4 __attribute__((ext_vector_type(4)));
typedef __bf16 bf16x8 __attribute__((ext_vector_type(8)));
typedef float  f32x4  __attribute__((ext_vector_type(4)));

#define MFMA(a, b, c) __builtin_amdgcn_mfma_f32_16x16x32_bf16((a), (b), (c), 0, 0, 0)

static constexpr int Bsz = 2, S = 2048, D = 1024, H = 16, DK = 64;

__device__ __forceinline__ bf16x8 pack8(float4 a, float4 b) {
    bf16x8 r;
    r[0] = (bf16_t)a.x; r[1] = (bf16_t)a.y; r[2] = (bf16_t)a.z; r[3] = (bf16_t)a.w;
    r[4] = (bf16_t)b.x; r[5] = (bf16_t)b.y; r[6] = (bf16_t)b.z; r[7] = (bf16_t)b.w;
    return r;
}

// ---------------------------------------------------------------------------
// Fused Q/K projection: z = blockIdx.z selects (x,Wq)->Q*0.125 or (z,Wk)->K+KT.
// C[M,N] = A[M,K]*B[N,K]^T + bias. 128x128 tile, BK=32, 512 threads (8 waves,
// 4x2 of 32x64), register-prefetch double-buffered LDS, 1 barrier/K-step.
// ---------------------------------------------------------------------------
__global__ __launch_bounds__(512) void gemm_qk(
    const float* __restrict__ xA, const float* __restrict__ wqB,
    const float* __restrict__ wqb, bf16_t* __restrict__ Qc,
    const float* __restrict__ zA, const float* __restrict__ wkB,
    const float* __restrict__ wkb, bf16_t* __restrict__ Kc,
    bf16_t* __restrict__ KTout)
{
    constexpr int M = Bsz * S, N = D, K = D;
    const int zi = blockIdx.z;
    const float* A    = zi ? zA  : xA;
    const float* B    = zi ? wkB : wqB;
    const float* bias = zi ? wkb : wqb;
    bf16_t*      C    = zi ? Kc  : Qc;
    const float  sc   = zi ? 1.f : 0.125f;   // fold softmax scale into Q

    __shared__ bf16_t As[2][128][40];
    __shared__ bf16_t Bs[2][128][40];

    const int t    = threadIdx.x;
    const int wave = t >> 6, lane = t & 63;
    const int quad = lane >> 4, l15 = lane & 15;
    const int wm = (wave >> 1) * 32, wn = (wave & 1) * 64;
    const int rowbase = blockIdx.y * 128, colbase = blockIdx.x * 128;
    const int r  = t >> 2;            // staging row 0..127
    const int cc = (t & 3) << 3;      // staging col 0,8,16,24

    f32x4 acc[2][4];
#pragma unroll
    for (int i = 0; i < 2; ++i)
#pragma unroll
        for (int j = 0; j < 4; ++j) acc[i][j] = {0.f, 0.f, 0.f, 0.f};

    // prologue: load + stage kt=0
    float4 a0 = *(const float4*)&A[(size_t)(rowbase + r) * K + cc];
    float4 a1 = *(const float4*)&A[(size_t)(rowbase + r) * K + cc + 4];
    float4 b0 = *(const float4*)&B[(size_t)(colbase + r) * K + cc];
    float4 b1 = *(const float4*)&B[(size_t)(colbase + r) * K + cc + 4];
    *(bf16x8*)&As[0][r][cc] = pack8(a0, a1);
    *(bf16x8*)&Bs[0][r][cc] = pack8(b0, b1);
    __syncthreads();

    for (int kt = 0; kt < K; kt += 32) {
        const int cur = (kt >> 5) & 1, nxt = cur ^ 1;
        const bool more = (kt + 32) < K;
        if (more) {
            a0 = *(const float4*)&A[(size_t)(rowbase + r) * K + kt + 32 + cc];
            a1 = *(const float4*)&A[(size_t)(rowbase + r) * K + kt + 32 + cc + 4];
            b0 = *(const float4*)&B[(size_t)(colbase + r) * K + kt + 32 + cc];
            b1 = *(const float4*)&B[(size_t)(colbase + r) * K + kt + 32 + cc + 4];
        }

        bf16x8 af[2], bfr[4];
#pragma unroll
        for (int mt = 0; mt < 2; ++mt)
            af[mt] = *(const bf16x8*)&As[cur][wm + mt * 16 + l15][quad * 8];
#pragma unroll
        for (int nt = 0; nt < 4; ++nt)
            bfr[nt] = *(const bf16x8*)&Bs[cur][wn + nt * 16 + l15][quad * 8];
#pragma unroll
        for (int mt = 0; mt < 2; ++mt)
#pragma unroll
            for (int nt = 0; nt < 4; ++nt)
                acc[mt][nt] = MFMA(af[mt], bfr[nt], acc[mt][nt]);

        if (more) {
            *(bf16x8*)&As[nxt][r][cc] = pack8(a0, a1);
            *(bf16x8*)&Bs[nxt][r][cc] = pack8(b0, b1);
        }
        __syncthreads();
    }

#pragma unroll
    for (int nt = 0; nt < 4; ++nt) {
        int col  = colbase + wn + nt * 16 + l15;
        float bv = bias[col];
#pragma unroll
        for (int mt = 0; mt < 2; ++mt) {
            int row0 = rowbase + wm + mt * 16 + quad * 4;
#pragma unroll
            for (int rr = 0; rr < 4; ++rr) {
                float v = (acc[mt][nt][rr] + bv) * sc;
                C[(size_t)(row0 + rr) * N + col] = (bf16_t)v;
                if (zi) {
                    int row = row0 + rr;                    // b*S + s
                    int bb = row >> 11, srow = row & (S - 1);
                    int hh = col >> 6,  dd   = col & 63;
                    KTout[(((size_t)bb * H + hh) * DK + dd) * S + srow] = (bf16_t)v;
                }
            }
        }
    }
}

// ---------------------------------------------------------------------------
// Output projection: C[M,N](f32) = A[M,K](bf16) * B[N,K](f32)^T + bias.
// Same 8-wave prefetch-pipelined structure.
// ---------------------------------------------------------------------------
__global__ __launch_bounds__(512) void gemm_obt(
    const bf16_t* __restrict__ A, const float* __restrict__ B,
    const float* __restrict__ bias, float* __restrict__ C)
{
    constexpr int M = Bsz * S, N = D, K = D;
    __shared__ bf16_t As[2][128][40];
    __shared__ bf16_t Bs[2][128][40];

    const int t    = threadIdx.x;
    const int wave = t >> 6, lane = t & 63;
    const int quad = lane >> 4, l15 = lane & 15;
    const int wm = (wave >> 1) * 32, wn = (wave & 1) * 64;
    const int rowbase = blockIdx.y * 128, colbase = blockIdx.x * 128;
    const int r  = t >> 2;
    const int cc = (t & 3) << 3;

    f32x4 acc[2][4];
#pragma unroll
    for (int i = 0; i < 2; ++i)
#pragma unroll
        for (int j = 0; j < 4; ++j) acc[i][j] = {0.f, 0.f, 0.f, 0.f};

    bf16x8 areg = *(const bf16x8*)&A[(size_t)(rowbase + r) * K + cc];
    float4 b0   = *(const float4*)&B[(size_t)(colbase + r) * K + cc];
    float4 b1   = *(const float4*)&B[(size_t)(colbase + r) * K + cc + 4];
    *(bf16x8*)&As[0][r][cc] = areg;
    *(bf16x8*)&Bs[0][r][cc] = pack8(b0, b1);
    __syncthreads();

    for (int kt = 0; kt < K; kt += 32) {
        const int cur = (kt >> 5) & 1, nxt = cur ^ 1;
        const bool more = (kt + 32) < K;
        if (more) {
            areg = *(const bf16x8*)&A[(size_t)(rowbase + r) * K + kt + 32 + cc];
            b0   = *(const float4*)&B[(size_t)(colbase + r) * K + kt + 32 + cc];
            b1   = *(const float4*)&B[(size_t)(colbase + r) * K + kt + 32 + cc + 4];
        }

        bf16x8 af[2], bfr[4];
#pragma unroll
        for (int mt = 0; mt < 2; ++mt)
            af[mt] = *(const bf16x8*)&As[cur][wm + mt * 16 + l15][quad * 8];
#pragma unroll
        for (int nt = 0; nt < 4; ++nt)
            bfr[nt] = *(const bf16x8*)&Bs[cur][wn + nt * 16 + l15][quad * 8];
#pragma unroll
        for (int mt = 0; mt < 2; ++mt)
#pragma unroll
            for (int nt = 0; nt < 4; ++nt)
                acc[mt][nt] = MFMA(af[mt], bfr[nt], acc[mt][nt]);

        if (more) {
            *(bf16x8*)&As[nxt][r][cc] = areg;
            *(bf16x8*)&Bs[nxt][r][cc] = pack8(b0, b1);
        }
        __syncthreads();
    }

#pragma unroll
    for (int nt = 0; nt < 4; ++nt) {
        int col  = colbase + wn + nt * 16 + l15;
        float bv = bias[col];
#pragma unroll
        for (int mt = 0; mt < 2; ++mt) {
            int row0 = rowbase + wm + mt * 16 + quad * 4;
#pragma unroll
            for (int rr = 0; rr < 4; ++rr)
                C[(size_t)(row0 + rr) * N + col] = acc[mt][nt][rr] + bv;
        }
    }
}

// ---------------------------------------------------------------------------
// Flash attention (causal, V == K), S^T formulation, prefetch-pipelined,
// diagonal tile split out of the main loop (off-diag iters carry no mask
// VALU). Q is pre-scaled by 0.125 (folded into the Q projection).
// ---------------------------------------------------------------------------
__global__ __launch_bounds__(256) void attn_flash(
    const bf16_t* __restrict__ Q, const bf16_t* __restrict__ Km,
    const bf16_t* __restrict__ KT,
    bf16_t* __restrict__ Oc, float* __restrict__ m_ws, float* __restrict__ il_ws)
{
    const int h = blockIdx.y, b = blockIdx.z;
    const int t = threadIdx.x;
    const int wave = t >> 6, lane = t & 63;
    const int quad = lane >> 4, l15 = lane & 15;

    __shared__ bf16_t Ks[2][64][72];
    __shared__ bf16_t KTs[2][64][72];
    __shared__ bf16_t PQ[64][72];

    const int hcol = h * DK;
    const bf16_t* KTh = KT + ((size_t)(b * H + h)) * DK * S;
    const size_t bS = (size_t)b * S;

    const int jr = (t >> 3);
    const int ce = (t & 7) * 8;
    const int iloc = wave * 16 + l15;

    for (int half = 0; half < 2; ++half) {
        const int qt = half == 0 ? (int)blockIdx.x : 31 - (int)blockIdx.x;
        const size_t qrow0 = bS + (size_t)qt * 64;

        __syncthreads();   // buffers reused across halves
        bf16x8 qld[2], kreg[2], ktreg[2];
#pragma unroll
        for (int p = 0; p < 2; ++p) {
            qld[p]   = *(const bf16x8*)&Q[(qrow0 + p * 32 + jr) * D + hcol + ce];
            kreg[p]  = *(const bf16x8*)&Km[(bS + p * 32 + jr) * D + hcol + ce];
            ktreg[p] = *(const bf16x8*)&KTh[(size_t)(p * 32 + jr) * S + ce];
        }
#pragma unroll
        for (int p = 0; p < 2; ++p) {
            *(bf16x8*)&PQ[p * 32 + jr][ce]     = qld[p];
            *(bf16x8*)&Ks[0][p * 32 + jr][ce]  = kreg[p];
            *(bf16x8*)&KTs[0][p * 32 + jr][ce] = ktreg[p];
        }
        __syncthreads();
        const bf16x8 qf0 = *(const bf16x8*)&PQ[wave * 16 + l15][quad * 8];
        const bf16x8 qf1 = *(const bf16x8*)&PQ[wave * 16 + l15][32 + quad * 8];

        f32x4 accO[4];
#pragma unroll
        for (int u = 0; u < 4; ++u) accO[u] = {0.f, 0.f, 0.f, 0.f};
        float m_cur = -1e30f, l_cur = 0.f;

        // softmax + PV for one staged tile (sv holds raw scores on entry)
        auto softmax_pv = [&](f32x4 sv[4], int cur) {
            float tm = sv[0][0];
#pragma unroll
            for (int nt = 0; nt < 4; ++nt)
#pragma unroll
                for (int r = 0; r < 4; ++r) tm = fmaxf(tm, sv[nt][r]);
            tm = fmaxf(tm, __shfl_xor(tm, 16));
            tm = fmaxf(tm, __shfl_xor(tm, 32));
            float m_new = fmaxf(m_cur, tm);
            float alpha = __expf(m_cur - m_new);
            m_cur = m_new;
            float rs = 0.f;
#pragma unroll
            for (int nt = 0; nt < 4; ++nt)
#pragma unroll
                for (int r = 0; r < 4; ++r) {
                    float p = __expf(sv[nt][r] - m_new);
                    sv[nt][r] = p;
                    rs += p;
                }
            rs += __shfl_xor(rs, 16);
            rs += __shfl_xor(rs, 32);
            l_cur = l_cur * alpha + rs;

            float alpha4[4];
#pragma unroll
            for (int r = 0; r < 4; ++r)
                alpha4[r] = __shfl(alpha, (quad << 4) + quad * 4 + r, 64);
#pragma unroll
            for (int u = 0; u < 4; ++u)
#pragma unroll
                for (int r = 0; r < 4; ++r) accO[u][r] *= alpha4[r];

#pragma unroll
            for (int nt = 0; nt < 4; ++nt) {
                bf16x4 pk;
                pk[0] = (bf16_t)sv[nt][0]; pk[1] = (bf16_t)sv[nt][1];
                pk[2] = (bf16_t)sv[nt][2]; pk[3] = (bf16_t)sv[nt][3];
                *(bf16x4*)&PQ[wave * 16 + l15][nt * 16 + quad * 4] = pk;
            }
            asm volatile("s_waitcnt lgkmcnt(0)" ::: "memory");  // wave-private

            bf16x8 pa0 = *(const bf16x8*)&PQ[wave * 16 + l15][quad * 8];
            bf16x8 pa1 = *(const bf16x8*)&PQ[wave * 16 + l15][32 + quad * 8];
#pragma unroll
            for (int u = 0; u < 4; ++u) {
                bf16x8 v0 = *(const bf16x8*)&KTs[cur][u * 16 + l15][quad * 8];
                bf16x8 v1 = *(const bf16x8*)&KTs[cur][u * 16 + l15][32 + quad * 8];
                accO[u] = MFMA(pa0, v0, accO[u]);
                accO[u] = MFMA(pa1, v1, accO[u]);
            }
        };

        // ---- off-diagonal iterations (no mask VALU)
        for (int jt = 0; jt < qt; ++jt) {
            const int cur = jt & 1, nxt = cur ^ 1;
#pragma unroll
            for (int p = 0; p < 2; ++p) {
                kreg[p]  = *(const bf16x8*)&Km[(bS + (size_t)(jt + 1) * 64 + p * 32 + jr) * D + hcol + ce];
                ktreg[p] = *(const bf16x8*)&KTh[(size_t)(p * 32 + jr) * S + (size_t)(jt + 1) * 64 + ce];
            }

            f32x4 sv[4];
#pragma unroll
            for (int nt = 0; nt < 4; ++nt) {
                bf16x8 a0 = *(const bf16x8*)&Ks[cur][nt * 16 + l15][quad * 8];
                bf16x8 a1 = *(const bf16x8*)&Ks[cur][nt * 16 + l15][32 + quad * 8];
                f32x4 a = {0.f, 0.f, 0.f, 0.f};
                a = MFMA(a0, qf0, a);
                a = MFMA(a1, qf1, a);
                sv[nt] = a;
            }
            softmax_pv(sv, cur);

#pragma unroll
            for (int p = 0; p < 2; ++p) {
                *(bf16x8*)&Ks[nxt][p * 32 + jr][ce]  = kreg[p];
                *(bf16x8*)&KTs[nxt][p * 32 + jr][ce] = ktreg[p];
            }
            __syncthreads();
        }

        // ---- diagonal tile
        {
            const int cur = qt & 1;
            f32x4 sv[4];
#pragma unroll
            for (int nt = 0; nt < 4; ++nt) {
                bf16x8 a0 = *(const bf16x8*)&Ks[cur][nt * 16 + l15][quad * 8];
                bf16x8 a1 = *(const bf16x8*)&Ks[cur][nt * 16 + l15][32 + quad * 8];
                f32x4 a = {0.f, 0.f, 0.f, 0.f};
                a = MFMA(a0, qf0, a);
                a = MFMA(a1, qf1, a);
#pragma unroll
                for (int r = 0; r < 4; ++r)
                    if ((nt * 16 + quad * 4 + r) > iloc) a[r] = -1e30f;
                sv[nt] = a;
            }
            softmax_pv(sv, cur);
        }

        float invl = 1.f / l_cur;
        float invl4[4];
#pragma unroll
        for (int r = 0; r < 4; ++r)
            invl4[r] = __shfl(invl, (quad << 4) + quad * 4 + r, 64);
#pragma unroll
        for (int u = 0; u < 4; ++u)
#pragma unroll
            for (int r = 0; r < 4; ++r)
                Oc[(qrow0 + wave * 16 + quad * 4 + r) * D + hcol + u * 16 + l15] =
                    (bf16_t)(accO[u][r] * invl4[r]);

        if (quad == 0) {
            size_t sb = ((size_t)(b * H + h)) * S + (size_t)qt * 64 + wave * 16 + l15;
            m_ws[sb]  = m_cur;
            il_ws[sb] = invl;
        }
    }
}

// ---------------------------------------------------------------------------
// Head-summed attention weights (f32): out2[b,i,j] = sum_h exp(s - m)/l.
// Q pre-scaled; prefetch-pipelined over heads.
// ---------------------------------------------------------------------------
__global__ __launch_bounds__(256) void attn_wsum(
    const bf16_t* __restrict__ Q, const bf16_t* __restrict__ Km,
    const float* __restrict__ m_ws, const float* __restrict__ il_ws,
    float* __restrict__ out2)
{
    const int jt = blockIdx.x, qt = blockIdx.y, b = blockIdx.z;
    const int t  = threadIdx.x;
    float* tile = out2 + (size_t)b * S * S + (size_t)qt * 64 * S + (size_t)jt * 64;

    if (jt > qt) {
        int r0 = t >> 2, c0 = (t & 3) * 16;
#pragma unroll
        for (int e = 0; e < 16; ++e) tile[(size_t)r0 * S + c0 + e] = 0.f;
        return;
    }

    const int wave = t >> 6, lane = t & 63;
    const int quad = lane >> 4, l15 = lane & 15;
    __shared__ bf16_t Ks[2][64][72];
    __shared__ bf16_t Qs[2][64][72];

    const int jr = (t >> 3), ce = (t & 7) * 8;
    const size_t krow = (size_t)b * S + (size_t)jt * 64;
    const size_t qrow = (size_t)b * S + (size_t)qt * 64;

    f32x4 accs[4];
#pragma unroll
    for (int nt = 0; nt < 4; ++nt) accs[nt] = {0.f, 0.f, 0.f, 0.f};

    bf16x8 kreg[2], qreg[2];
#pragma unroll
    for (int p = 0; p < 2; ++p) {
        kreg[p] = *(const bf16x8*)&Km[(krow + p * 32 + jr) * D + ce];
        qreg[p] = *(const bf16x8*)&Q[(qrow + p * 32 + jr) * D + ce];
    }
#pragma unroll
    for (int p = 0; p < 2; ++p) {
        *(bf16x8*)&Ks[0][p * 32 + jr][ce] = kreg[p];
        *(bf16x8*)&Qs[0][p * 32 + jr][ce] = qreg[p];
    }
    __syncthreads();

    for (int h = 0; h < H; ++h) {
        const int cur = h & 1, nxt = cur ^ 1;

        if (h < H - 1) {
            const int hc = (h + 1) * DK;
#pragma unroll
            for (int p = 0; p < 2; ++p) {
                kreg[p] = *(const bf16x8*)&Km[(krow + p * 32 + jr) * D + hc + ce];
                qreg[p] = *(const bf16x8*)&Q[(qrow + p * 32 + jr) * D + hc + ce];
            }
        }

        bf16x8 qf0 = *(const bf16x8*)&Qs[cur][wave * 16 + l15][quad * 8];
        bf16x8 qf1 = *(const bf16x8*)&Qs[cur][wave * 16 + l15][32 + quad * 8];

        size_t mlb = ((size_t)(b * H + h)) * S + (size_t)qt * 64 + wave * 16 + quad * 4;
        f32x4 mr = *(const f32x4*)&m_ws[mlb];
        f32x4 il = *(const f32x4*)&il_ws[mlb];

#pragma unroll
        for (int nt = 0; nt < 4; ++nt) {
            bf16x8 k0 = *(const bf16x8*)&Ks[cur][nt * 16 + l15][quad * 8];
            bf16x8 k1 = *(const bf16x8*)&Ks[cur][nt * 16 + l15][32 + quad * 8];
            f32x4 a = {0.f, 0.f, 0.f, 0.f};
            a = MFMA(qf0, k0, a);
            a = MFMA(qf1, k1, a);
#pragma unroll
            for (int r = 0; r < 4; ++r) {
                int i = qt * 64 + wave * 16 + quad * 4 + r;
                int j = jt * 64 + nt * 16 + l15;
                float p = (j <= i) ? __expf(a[r] - mr[r]) * il[r] : 0.f;
                accs[nt][r] += p;
            }
        }

        if (h < H - 1) {
#pragma unroll
            for (int p = 0; p < 2; ++p) {
                *(bf16x8*)&Ks[nxt][p * 32 + jr][ce] = kreg[p];
                *(bf16x8*)&Qs[nxt][p * 32 + jr][ce] = qreg[p];
            }
        }
        __syncthreads();
    }

#pragma unroll
    for (int nt = 0; nt < 4; ++nt)
#pragma unroll
        for (int r = 0; r < 4; ++r)
            tile[(size_t)(wave * 16 + quad * 4 + r) * S + nt * 16 + l15] = accs[nt][r];
}

// ---------------------------------------------------------------------------
extern "C" void kernel_launch(void* const* d_in, const int* in_sizes, int n_in,
                              void* d_out, int out_size, void* d_ws, size_t ws_size,
                              hipStream_t stream)
{
    const float* x    = (const float*)d_in[0];
    const float* z    = (const float*)d_in[1];
    // d_in[2] = causal mask (int32 tril) -- structure exploited directly
    const float* wq_w = (const float*)d_in[3];
    const float* wq_b = (const float*)d_in[4];
    const float* wk_w = (const float*)d_in[5];
    const float* wk_b = (const float*)d_in[6];
    // d_in[7], d_in[8] = wv (dead parameter: reference uses wk for V)
    const float* wo_w = (const float*)d_in[9];
    const float* wo_b = (const float*)d_in[10];

    float* out  = (float*)d_out;                    // chunk 0: [B,S,D] f32
    float* out2 = out + (size_t)Bsz * S * D;        // chunk 1: [B,S,S] f32 (32 MB)

    // Workspace (16.5 MB): stats + internal bf16 Q (pre-scaled by 0.125), K.
    float*  m_ws  = (float*)d_ws;
    float*  il_ws = m_ws + (size_t)Bsz * H * S;
    bf16_t* Qws   = (bf16_t*)(il_ws + (size_t)Bsz * H * S);
    bf16_t* Kws   = Qws + (size_t)Bsz * S * D;
    // Scratch parked inside out2's 32 MB (both dead before attn_wsum runs):
    bf16_t* Cc    = (bf16_t*)out2;                  // concat  [B*S, D]  (8 MB)
    bf16_t* KTws  = Cc + (size_t)Bsz * S * D;       // K^T [B,H,DK,S]    (8 MB)

    gemm_qk<<<dim3(D / 128, (Bsz * S) / 128, 2), dim3(512), 0, stream>>>(
        x, wq_w, wq_b, Qws, z, wk_w, wk_b, Kws, KTws);
    attn_flash<<<dim3(S / 128, H, Bsz), dim3(256), 0, stream>>>(
        Qws, Kws, KTws, Cc, m_ws, il_ws);
    gemm_obt<<<dim3(D / 128, (Bsz * S) / 128, 1), dim3(512), 0, stream>>>(
        Cc, wo_w, wo_b, out);
    attn_wsum<<<dim3(S / 64, S / 64, Bsz), dim3(256), 0, stream>>>(
        Qws, Kws, m_ws, il_ws, out2);
}

// Round 9
// 265.076 us; speedup vs baseline: 1.7279x; 1.0819x over previous
//
#include <hip/hip_runtime.h>

typedef __bf16 bf16_t;
typedef __bf16 bf16x4 __attribute__((ext_vector_type(4)));
typedef __bf16 bf16x8 __attribute__((ext_vector_type(8)));
typedef float  f32x4  __attribute__((ext_vector_type(4)));

#define MFMA(a, b, c) __builtin_amdgcn_mfma_f32_16x16x32_bf16((a), (b), (c), 0, 0, 0)

static constexpr int Bsz = 2, S = 2048, D = 1024, H = 16, DK = 64;

// ---------------------------------------------------------------------------
// One-pass f32 -> bf16 conversion of x, z, wq, wk, wo. Each thread converts
// one float4. Segment boundaries are multiples of 64 -> wave-uniform branches.
// ---------------------------------------------------------------------------
__global__ __launch_bounds__(256) void cvt5(
    const float* __restrict__ x, const float* __restrict__ z,
    const float* __restrict__ wq, const float* __restrict__ wk,
    const float* __restrict__ wo,
    bf16_t* __restrict__ xb, bf16_t* __restrict__ zb,
    bf16_t* __restrict__ wqb, bf16_t* __restrict__ wkb, bf16_t* __restrict__ wob)
{
    constexpr int NXZ = Bsz * S * D / 4;   // 1,048,576 float4 chunks
    constexpr int NW  = D * D / 4;         //   262,144
    int i = blockIdx.x * 256 + threadIdx.x;
    const float* s; bf16_t* d; int off;
    if (i < NXZ)                 { s = x;  d = xb;  off = i; }
    else if (i < 2 * NXZ)        { s = z;  d = zb;  off = i - NXZ; }
    else if (i < 2 * NXZ + NW)   { s = wq; d = wqb; off = i - 2 * NXZ; }
    else if (i < 2 * NXZ + 2*NW) { s = wk; d = wkb; off = i - 2 * NXZ - NW; }
    else                         { s = wo; d = wob; off = i - 2 * NXZ - 2 * NW; }
    float4 v = *(const float4*)&s[(size_t)off * 4];
    bf16x4 o;
    o[0] = (bf16_t)v.x; o[1] = (bf16_t)v.y; o[2] = (bf16_t)v.z; o[3] = (bf16_t)v.w;
    *(bf16x4*)&d[(size_t)off * 4] = o;
}

// ---------------------------------------------------------------------------
// Fused Q/K projection, all-bf16 operands. blockIdx.z selects
// (xb,wqb)->Q*0.125 or (zb,wkb)->K + KT. 128x128 tile, BK=32, 512 threads
// (8 waves, 4x2 of 32x64), register-prefetch dbuf LDS, 1 barrier/K-step.
// ---------------------------------------------------------------------------
__global__ __launch_bounds__(512) void gemm_qk(
    const bf16_t* __restrict__ xA, const bf16_t* __restrict__ wqB,
    const float* __restrict__ wqb, bf16_t* __restrict__ Qc,
    const bf16_t* __restrict__ zA, const bf16_t* __restrict__ wkB,
    const float* __restrict__ wkb, bf16_t* __restrict__ Kc,
    bf16_t* __restrict__ KTout)
{
    constexpr int N = D, K = D;
    const int zi = blockIdx.z;
    const bf16_t* A    = zi ? zA  : xA;
    const bf16_t* B    = zi ? wkB : wqB;
    const float*  bias = zi ? wkb : wqb;
    bf16_t*       C    = zi ? Kc  : Qc;
    const float   sc   = zi ? 1.f : 0.125f;   // fold softmax scale into Q

    __shared__ bf16_t As[2][128][40];
    __shared__ bf16_t Bs[2][128][40];

    const int t    = threadIdx.x;
    const int wave = t >> 6, lane = t & 63;
    const int quad = lane >> 4, l15 = lane & 15;
    const int wm = (wave >> 1) * 32, wn = (wave & 1) * 64;
    const int rowbase = blockIdx.y * 128, colbase = blockIdx.x * 128;
    const int r  = t >> 2;            // staging row 0..127
    const int cc = (t & 3) << 3;      // staging col 0,8,16,24

    f32x4 acc[2][4];
#pragma unroll
    for (int i = 0; i < 2; ++i)
#pragma unroll
        for (int j = 0; j < 4; ++j) acc[i][j] = {0.f, 0.f, 0.f, 0.f};

    bf16x8 areg = *(const bf16x8*)&A[(size_t)(rowbase + r) * K + cc];
    bf16x8 breg = *(const bf16x8*)&B[(size_t)(colbase + r) * K + cc];
    *(bf16x8*)&As[0][r][cc] = areg;
    *(bf16x8*)&Bs[0][r][cc] = breg;
    __syncthreads();

    for (int kt = 0; kt < K; kt += 32) {
        const int cur = (kt >> 5) & 1, nxt = cur ^ 1;
        const bool more = (kt + 32) < K;
        if (more) {
            areg = *(const bf16x8*)&A[(size_t)(rowbase + r) * K + kt + 32 + cc];
            breg = *(const bf16x8*)&B[(size_t)(colbase + r) * K + kt + 32 + cc];
        }

        bf16x8 af[2], bfr[4];
#pragma unroll
        for (int mt = 0; mt < 2; ++mt)
            af[mt] = *(const bf16x8*)&As[cur][wm + mt * 16 + l15][quad * 8];
#pragma unroll
        for (int nt = 0; nt < 4; ++nt)
            bfr[nt] = *(const bf16x8*)&Bs[cur][wn + nt * 16 + l15][quad * 8];
#pragma unroll
        for (int mt = 0; mt < 2; ++mt)
#pragma unroll
            for (int nt = 0; nt < 4; ++nt)
                acc[mt][nt] = MFMA(af[mt], bfr[nt], acc[mt][nt]);

        if (more) {
            *(bf16x8*)&As[nxt][r][cc] = areg;
            *(bf16x8*)&Bs[nxt][r][cc] = breg;
        }
        __syncthreads();
    }

#pragma unroll
    for (int nt = 0; nt < 4; ++nt) {
        int col  = colbase + wn + nt * 16 + l15;
        float bv = bias[col];
#pragma unroll
        for (int mt = 0; mt < 2; ++mt) {
            int row0 = rowbase + wm + mt * 16 + quad * 4;
#pragma unroll
            for (int rr = 0; rr < 4; ++rr) {
                float v = (acc[mt][nt][rr] + bv) * sc;
                C[(size_t)(row0 + rr) * N + col] = (bf16_t)v;
                if (zi) {
                    int row = row0 + rr;                    // b*S + s
                    int bb = row >> 11, srow = row & (S - 1);
                    int hh = col >> 6,  dd   = col & 63;
                    KTout[(((size_t)bb * H + hh) * DK + dd) * S + srow] = (bf16_t)v;
                }
            }
        }
    }
}

// ---------------------------------------------------------------------------
// Output projection: C[M,N](f32) = Cc[M,K](bf16) * wo[N,K](bf16)^T + bias.
// 64x128 tile, 256 threads (4 waves, 2x2 of 32x64), grid 512 (2 blocks/CU),
// register-prefetch dbuf, 1 barrier/K-step.
// ---------------------------------------------------------------------------
__global__ __launch_bounds__(256) void gemm_obt(
    const bf16_t* __restrict__ A, const bf16_t* __restrict__ B,
    const float* __restrict__ bias, float* __restrict__ C)
{
    constexpr int N = D, K = D;
    __shared__ bf16_t As[2][64][40];
    __shared__ bf16_t Bs[2][128][40];

    const int t    = threadIdx.x;
    const int wave = t >> 6, lane = t & 63;
    const int quad = lane >> 4, l15 = lane & 15;
    const int wm = (wave >> 1) * 32, wn = (wave & 1) * 64;
    const int rowbase = blockIdx.y * 64, colbase = blockIdx.x * 128;
    const int r  = t >> 2;            // 0..63
    const int cc = (t & 3) << 3;

    f32x4 acc[2][4];
#pragma unroll
    for (int i = 0; i < 2; ++i)
#pragma unroll
        for (int j = 0; j < 4; ++j) acc[i][j] = {0.f, 0.f, 0.f, 0.f};

    bf16x8 areg = *(const bf16x8*)&A[(size_t)(rowbase + r) * K + cc];
    bf16x8 breg0 = *(const bf16x8*)&B[(size_t)(colbase + r) * K + cc];
    bf16x8 breg1 = *(const bf16x8*)&B[(size_t)(colbase + 64 + r) * K + cc];
    *(bf16x8*)&As[0][r][cc]      = areg;
    *(bf16x8*)&Bs[0][r][cc]      = breg0;
    *(bf16x8*)&Bs[0][64 + r][cc] = breg1;
    __syncthreads();

    for (int kt = 0; kt < K; kt += 32) {
        const int cur = (kt >> 5) & 1, nxt = cur ^ 1;
        const bool more = (kt + 32) < K;
        if (more) {
            areg  = *(const bf16x8*)&A[(size_t)(rowbase + r) * K + kt + 32 + cc];
            breg0 = *(const bf16x8*)&B[(size_t)(colbase + r) * K + kt + 32 + cc];
            breg1 = *(const bf16x8*)&B[(size_t)(colbase + 64 + r) * K + kt + 32 + cc];
        }

        bf16x8 af[2], bfr[4];
#pragma unroll
        for (int mt = 0; mt < 2; ++mt)
            af[mt] = *(const bf16x8*)&As[cur][wm + mt * 16 + l15][quad * 8];
#pragma unroll
        for (int nt = 0; nt < 4; ++nt)
            bfr[nt] = *(const bf16x8*)&Bs[cur][wn + nt * 16 + l15][quad * 8];
#pragma unroll
        for (int mt = 0; mt < 2; ++mt)
#pragma unroll
            for (int nt = 0; nt < 4; ++nt)
                acc[mt][nt] = MFMA(af[mt], bfr[nt], acc[mt][nt]);

        if (more) {
            *(bf16x8*)&As[nxt][r][cc]      = areg;
            *(bf16x8*)&Bs[nxt][r][cc]      = breg0;
            *(bf16x8*)&Bs[nxt][64 + r][cc] = breg1;
        }
        __syncthreads();
    }

#pragma unroll
    for (int nt = 0; nt < 4; ++nt) {
        int col  = colbase + wn + nt * 16 + l15;
        float bv = bias[col];
#pragma unroll
        for (int mt = 0; mt < 2; ++mt) {
            int row0 = rowbase + wm + mt * 16 + quad * 4;
#pragma unroll
            for (int rr = 0; rr < 4; ++rr)
                C[(size_t)(row0 + rr) * N + col] = acc[mt][nt][rr] + bv;
        }
    }
}

// ---------------------------------------------------------------------------
// Flash attention (causal, V == K), S^T formulation, prefetch-pipelined,
// diagonal tile split out. Q pre-scaled by 0.125.
// ---------------------------------------------------------------------------
__global__ __launch_bounds__(256) void attn_flash(
    const bf16_t* __restrict__ Q, const bf16_t* __restrict__ Km,
    const bf16_t* __restrict__ KT,
    bf16_t* __restrict__ Oc, float* __restrict__ m_ws, float* __restrict__ il_ws)
{
    const int h = blockIdx.y, b = blockIdx.z;
    const int t = threadIdx.x;
    const int wave = t >> 6, lane = t & 63;
    const int quad = lane >> 4, l15 = lane & 15;

    __shared__ bf16_t Ks[2][64][72];
    __shared__ bf16_t KTs[2][64][72];
    __shared__ bf16_t PQ[64][72];

    const int hcol = h * DK;
    const bf16_t* KTh = KT + ((size_t)(b * H + h)) * DK * S;
    const size_t bS = (size_t)b * S;

    const int jr = (t >> 3);
    const int ce = (t & 7) * 8;
    const int iloc = wave * 16 + l15;

    for (int half = 0; half < 2; ++half) {
        const int qt = half == 0 ? (int)blockIdx.x : 31 - (int)blockIdx.x;
        const size_t qrow0 = bS + (size_t)qt * 64;

        __syncthreads();   // buffers reused across halves
        bf16x8 qld[2], kreg[2], ktreg[2];
#pragma unroll
        for (int p = 0; p < 2; ++p) {
            qld[p]   = *(const bf16x8*)&Q[(qrow0 + p * 32 + jr) * D + hcol + ce];
            kreg[p]  = *(const bf16x8*)&Km[(bS + p * 32 + jr) * D + hcol + ce];
            ktreg[p] = *(const bf16x8*)&KTh[(size_t)(p * 32 + jr) * S + ce];
        }
#pragma unroll
        for (int p = 0; p < 2; ++p) {
            *(bf16x8*)&PQ[p * 32 + jr][ce]     = qld[p];
            *(bf16x8*)&Ks[0][p * 32 + jr][ce]  = kreg[p];
            *(bf16x8*)&KTs[0][p * 32 + jr][ce] = ktreg[p];
        }
        __syncthreads();
        const bf16x8 qf0 = *(const bf16x8*)&PQ[wave * 16 + l15][quad * 8];
        const bf16x8 qf1 = *(const bf16x8*)&PQ[wave * 16 + l15][32 + quad * 8];

        f32x4 accO[4];
#pragma unroll
        for (int u = 0; u < 4; ++u) accO[u] = {0.f, 0.f, 0.f, 0.f};
        float m_cur = -1e30f, l_cur = 0.f;

        auto softmax_pv = [&](f32x4 sv[4], int cur) {
            float tm = sv[0][0];
#pragma unroll
            for (int nt = 0; nt < 4; ++nt)
#pragma unroll
                for (int r = 0; r < 4; ++r) tm = fmaxf(tm, sv[nt][r]);
            tm = fmaxf(tm, __shfl_xor(tm, 16));
            tm = fmaxf(tm, __shfl_xor(tm, 32));
            float m_new = fmaxf(m_cur, tm);
            float alpha = __expf(m_cur - m_new);
            m_cur = m_new;
            float rs = 0.f;
#pragma unroll
            for (int nt = 0; nt < 4; ++nt)
#pragma unroll
                for (int r = 0; r < 4; ++r) {
                    float p = __expf(sv[nt][r] - m_new);
                    sv[nt][r] = p;
                    rs += p;
                }
            rs += __shfl_xor(rs, 16);
            rs += __shfl_xor(rs, 32);
            l_cur = l_cur * alpha + rs;

            float alpha4[4];
#pragma unroll
            for (int r = 0; r < 4; ++r)
                alpha4[r] = __shfl(alpha, (quad << 4) + quad * 4 + r, 64);
#pragma unroll
            for (int u = 0; u < 4; ++u)
#pragma unroll
                for (int r = 0; r < 4; ++r) accO[u][r] *= alpha4[r];

#pragma unroll
            for (int nt = 0; nt < 4; ++nt) {
                bf16x4 pk;
                pk[0] = (bf16_t)sv[nt][0]; pk[1] = (bf16_t)sv[nt][1];
                pk[2] = (bf16_t)sv[nt][2]; pk[3] = (bf16_t)sv[nt][3];
                *(bf16x4*)&PQ[wave * 16 + l15][nt * 16 + quad * 4] = pk;
            }
            asm volatile("s_waitcnt lgkmcnt(0)" ::: "memory");  // wave-private

            bf16x8 pa0 = *(const bf16x8*)&PQ[wave * 16 + l15][quad * 8];
            bf16x8 pa1 = *(const bf16x8*)&PQ[wave * 16 + l15][32 + quad * 8];
#pragma unroll
            for (int u = 0; u < 4; ++u) {
                bf16x8 v0 = *(const bf16x8*)&KTs[cur][u * 16 + l15][quad * 8];
                bf16x8 v1 = *(const bf16x8*)&KTs[cur][u * 16 + l15][32 + quad * 8];
                accO[u] = MFMA(pa0, v0, accO[u]);
                accO[u] = MFMA(pa1, v1, accO[u]);
            }
        };

        for (int jt = 0; jt < qt; ++jt) {
            const int cur = jt & 1, nxt = cur ^ 1;
#pragma unroll
            for (int p = 0; p < 2; ++p) {
                kreg[p]  = *(const bf16x8*)&Km[(bS + (size_t)(jt + 1) * 64 + p * 32 + jr) * D + hcol + ce];
                ktreg[p] = *(const bf16x8*)&KTh[(size_t)(p * 32 + jr) * S + (size_t)(jt + 1) * 64 + ce];
            }

            f32x4 sv[4];
#pragma unroll
            for (int nt = 0; nt < 4; ++nt) {
                bf16x8 a0 = *(const bf16x8*)&Ks[cur][nt * 16 + l15][quad * 8];
                bf16x8 a1 = *(const bf16x8*)&Ks[cur][nt * 16 + l15][32 + quad * 8];
                f32x4 a = {0.f, 0.f, 0.f, 0.f};
                a = MFMA(a0, qf0, a);
                a = MFMA(a1, qf1, a);
                sv[nt] = a;
            }
            softmax_pv(sv, cur);

#pragma unroll
            for (int p = 0; p < 2; ++p) {
                *(bf16x8*)&Ks[nxt][p * 32 + jr][ce]  = kreg[p];
                *(bf16x8*)&KTs[nxt][p * 32 + jr][ce] = ktreg[p];
            }
            __syncthreads();
        }

        {
            const int cur = qt & 1;
            f32x4 sv[4];
#pragma unroll
            for (int nt = 0; nt < 4; ++nt) {
                bf16x8 a0 = *(const bf16x8*)&Ks[cur][nt * 16 + l15][quad * 8];
                bf16x8 a1 = *(const bf16x8*)&Ks[cur][nt * 16 + l15][32 + quad * 8];
                f32x4 a = {0.f, 0.f, 0.f, 0.f};
                a = MFMA(a0, qf0, a);
                a = MFMA(a1, qf1, a);
#pragma unroll
                for (int r = 0; r < 4; ++r)
                    if ((nt * 16 + quad * 4 + r) > iloc) a[r] = -1e30f;
                sv[nt] = a;
            }
            softmax_pv(sv, cur);
        }

        float invl = 1.f / l_cur;
        float invl4[4];
#pragma unroll
        for (int r = 0; r < 4; ++r)
            invl4[r] = __shfl(invl, (quad << 4) + quad * 4 + r, 64);
#pragma unroll
        for (int u = 0; u < 4; ++u)
#pragma unroll
            for (int r = 0; r < 4; ++r)
                Oc[(qrow0 + wave * 16 + quad * 4 + r) * D + hcol + u * 16 + l15] =
                    (bf16_t)(accO[u][r] * invl4[r]);

        if (quad == 0) {
            size_t sb = ((size_t)(b * H + h)) * S + (size_t)qt * 64 + wave * 16 + l15;
            m_ws[sb]  = m_cur;
            il_ws[sb] = invl;
        }
    }
}

// ---------------------------------------------------------------------------
// Head-summed attention weights (f32): out2[b,i,j] = sum_h exp(s - m)/l.
// Q pre-scaled; prefetch-pipelined over heads.
// ---------------------------------------------------------------------------
__global__ __launch_bounds__(256) void attn_wsum(
    const bf16_t* __restrict__ Q, const bf16_t* __restrict__ Km,
    const float* __restrict__ m_ws, const float* __restrict__ il_ws,
    float* __restrict__ out2)
{
    const int jt = blockIdx.x, qt = blockIdx.y, b = blockIdx.z;
    const int t  = threadIdx.x;
    float* tile = out2 + (size_t)b * S * S + (size_t)qt * 64 * S + (size_t)jt * 64;

    if (jt > qt) {
        int r0 = t >> 2, c0 = (t & 3) * 16;
#pragma unroll
        for (int e = 0; e < 16; ++e) tile[(size_t)r0 * S + c0 + e] = 0.f;
        return;
    }

    const int wave = t >> 6, lane = t & 63;
    const int quad = lane >> 4, l15 = lane & 15;
    __shared__ bf16_t Ks[2][64][72];
    __shared__ bf16_t Qs[2][64][72];

    const int jr = (t >> 3), ce = (t & 7) * 8;
    const size_t krow = (size_t)b * S + (size_t)jt * 64;
    const size_t qrow = (size_t)b * S + (size_t)qt * 64;

    f32x4 accs[4];
#pragma unroll
    for (int nt = 0; nt < 4; ++nt) accs[nt] = {0.f, 0.f, 0.f, 0.f};

    bf16x8 kreg[2], qreg[2];
#pragma unroll
    for (int p = 0; p < 2; ++p) {
        kreg[p] = *(const bf16x8*)&Km[(krow + p * 32 + jr) * D + ce];
        qreg[p] = *(const bf16x8*)&Q[(qrow + p * 32 + jr) * D + ce];
    }
#pragma unroll
    for (int p = 0; p < 2; ++p) {
        *(bf16x8*)&Ks[0][p * 32 + jr][ce] = kreg[p];
        *(bf16x8*)&Qs[0][p * 32 + jr][ce] = qreg[p];
    }
    __syncthreads();

    for (int h = 0; h < H; ++h) {
        const int cur = h & 1, nxt = cur ^ 1;

        if (h < H - 1) {
            const int hc = (h + 1) * DK;
#pragma unroll
            for (int p = 0; p < 2; ++p) {
                kreg[p] = *(const bf16x8*)&Km[(krow + p * 32 + jr) * D + hc + ce];
                qreg[p] = *(const bf16x8*)&Q[(qrow + p * 32 + jr) * D + hc + ce];
            }
        }

        bf16x8 qf0 = *(const bf16x8*)&Qs[cur][wave * 16 + l15][quad * 8];
        bf16x8 qf1 = *(const bf16x8*)&Qs[cur][wave * 16 + l15][32 + quad * 8];

        size_t mlb = ((size_t)(b * H + h)) * S + (size_t)qt * 64 + wave * 16 + quad * 4;
        f32x4 mr = *(const f32x4*)&m_ws[mlb];
        f32x4 il = *(const f32x4*)&il_ws[mlb];

#pragma unroll
        for (int nt = 0; nt < 4; ++nt) {
            bf16x8 k0 = *(const bf16x8*)&Ks[cur][nt * 16 + l15][quad * 8];
            bf16x8 k1 = *(const bf16x8*)&Ks[cur][nt * 16 + l15][32 + quad * 8];
            f32x4 a = {0.f, 0.f, 0.f, 0.f};
            a = MFMA(qf0, k0, a);
            a = MFMA(qf1, k1, a);
#pragma unroll
            for (int r = 0; r < 4; ++r) {
                int i = qt * 64 + wave * 16 + quad * 4 + r;
                int j = jt * 64 + nt * 16 + l15;
                float p = (j <= i) ? __expf(a[r] - mr[r]) * il[r] : 0.f;
                accs[nt][r] += p;
            }
        }

        if (h < H - 1) {
#pragma unroll
            for (int p = 0; p < 2; ++p) {
                *(bf16x8*)&Ks[nxt][p * 32 + jr][ce] = kreg[p];
                *(bf16x8*)&Qs[nxt][p * 32 + jr][ce] = qreg[p];
            }
        }
        __syncthreads();
    }

#pragma unroll
    for (int nt = 0; nt < 4; ++nt)
#pragma unroll
        for (int r = 0; r < 4; ++r)
            tile[(size_t)(wave * 16 + quad * 4 + r) * S + nt * 16 + l15] = accs[nt][r];
}

// ---------------------------------------------------------------------------
extern "C" void kernel_launch(void* const* d_in, const int* in_sizes, int n_in,
                              void* d_out, int out_size, void* d_ws, size_t ws_size,
                              hipStream_t stream)
{
    const float* x    = (const float*)d_in[0];
    const float* z    = (const float*)d_in[1];
    // d_in[2] = causal mask (int32 tril) -- structure exploited directly
    const float* wq_w = (const float*)d_in[3];
    const float* wq_b = (const float*)d_in[4];
    const float* wk_w = (const float*)d_in[5];
    const float* wk_b = (const float*)d_in[6];
    // d_in[7], d_in[8] = wv (dead parameter: reference uses wk for V)
    const float* wo_w = (const float*)d_in[9];
    const float* wo_b = (const float*)d_in[10];

    float* out  = (float*)d_out;                    // chunk 0: [B,S,D] f32 (16.78 MB)
    float* out2 = out + (size_t)Bsz * S * D;        // chunk 1: [B,S,S] f32 (32 MB)

    // ws (23.6 MB): stats + bf16 Q (pre-scaled), K, and bf16 weights.
    float*  m_ws  = (float*)d_ws;
    float*  il_ws = m_ws + (size_t)Bsz * H * S;
    bf16_t* Qws   = (bf16_t*)(il_ws + (size_t)Bsz * H * S);
    bf16_t* Kws   = Qws + (size_t)Bsz * S * D;
    bf16_t* wq_bf = Kws + (size_t)Bsz * S * D;
    bf16_t* wk_bf = wq_bf + (size_t)D * D;
    bf16_t* wo_bf = wk_bf + (size_t)D * D;
    // bf16 x,z parked in out chunk 0 (exactly 16.78 MB; dead before gemm_obt
    // overwrites chunk 0 last-but-one).
    bf16_t* xb    = (bf16_t*)out;
    bf16_t* zb    = xb + (size_t)Bsz * S * D;
    // Cc + KT parked in out2 (16.8 of 32 MB; dead before attn_wsum runs last).
    bf16_t* Cc    = (bf16_t*)out2;                  // concat  [B*S, D]
    bf16_t* KTws  = Cc + (size_t)Bsz * S * D;       // K^T [B,H,DK,S]

    constexpr int CVT_BLOCKS = (2 * (Bsz * S * D / 4) + 3 * (D * D / 4)) / 256;
    cvt5<<<dim3(CVT_BLOCKS), dim3(256), 0, stream>>>(
        x, z, wq_w, wk_w, wo_w, xb, zb, wq_bf, wk_bf, wo_bf);
    gemm_qk<<<dim3(D / 128, (Bsz * S) / 128, 2), dim3(512), 0, stream>>>(
        xb, wq_bf, wq_b, Qws, zb, wk_bf, wk_b, Kws, KTws);
    attn_flash<<<dim3(S / 128, H, Bsz), dim3(256), 0, stream>>>(
        Qws, Kws, KTws, Cc, m_ws, il_ws);
    gemm_obt<<<dim3(D / 128, (Bsz * S) / 64, 1), dim3(256), 0, stream>>>(
        Cc, wo_bf, wo_b, out);
    attn_wsum<<<dim3(S / 64, S / 64, Bsz), dim3(256), 0, stream>>>(
        Qws, Kws, m_ws, il_ws, out2);
}